// Round 1
// baseline (811.079 us; speedup 1.0000x reference)
//
#include <hip/hip_runtime.h>

// Problem constants (fixed by setup_inputs)
constexpr int B = 4;
constexpr int C = 64;    // input channels
constexpr int O = 64;    // output channels (main conv)
constexpr int OOFF = 18; // offset channels = 2*3*3
constexpr int H = 192;
constexpr int W = 192;

// -------------------------------------------------------------------------
// Kernel 1: transpose x [B,C,H,W] -> xt [B,H,W,C] (channels-last) so the
// deformable gather can fetch 4 channels per float4 load.
// grid: (W/16, H, B), 256 threads
// -------------------------------------------------------------------------
__global__ __launch_bounds__(256) void k_transpose(const float* __restrict__ x,
                                                   float* __restrict__ xt) {
  __shared__ float tile[64][17];
  const int w0 = blockIdx.x * 16;
  const int h = blockIdx.y;
  const int b = blockIdx.z;
  const int tid = threadIdx.x;

  const int wl = tid & 15;
  const int c0 = tid >> 4; // 0..15
#pragma unroll
  for (int r = 0; r < 4; ++r) {
    const int c = c0 + r * 16;
    tile[c][wl] = x[(((size_t)b * C + c) * H + h) * W + w0 + wl];
  }
  __syncthreads();
  const int c = tid & 63;
  const int qq = tid >> 6; // 0..3
#pragma unroll
  for (int r = 0; r < 4; ++r) {
    const int wq = qq + r * 4;
    xt[(((size_t)b * H + h) * W + w0 + wq) * C + c] = tile[c][wq];
  }
}

// -------------------------------------------------------------------------
// Kernel 2: offset conv (3x3, C=64 -> 18, pad 1).
// Thread per pixel (16x16 tile), 18 accumulators, LDS-staged inputs.
// Weight LDS reads are wave-uniform -> broadcast (conflict-free).
// grid: (12, 12, 4), 256 threads
// -------------------------------------------------------------------------
__global__ __launch_bounds__(256) void k_conv_off(const float* __restrict__ x,
                                                  const float* __restrict__ w_off,
                                                  const float* __restrict__ b_off,
                                                  float* __restrict__ off) {
  constexpr int CB = 8;
  __shared__ float xs[CB][18][18];      // [c][ty][tx] halo tile
  __shared__ float ws[CB][9][OOFF];     // [c][k][o]
  const int w0 = blockIdx.x * 16, h0 = blockIdx.y * 16, b = blockIdx.z;
  const int tid = threadIdx.x;
  const int px = tid & 15, py = tid >> 4;

  float acc[OOFF];
#pragma unroll
  for (int o = 0; o < OOFF; ++o) acc[o] = 0.f;

  for (int cb = 0; cb < C / CB; ++cb) {
    // stage x halo tile
    for (int i = tid; i < CB * 18 * 18; i += 256) {
      const int cc = i / 324;
      const int rem = i - cc * 324;
      const int ty = rem / 18, tx = rem - (rem / 18) * 18;
      const int hh = h0 + ty - 1, ww = w0 + tx - 1;
      float v = 0.f;
      if (hh >= 0 && hh < H && ww >= 0 && ww < W)
        v = x[(((size_t)b * C + cb * CB + cc) * H + hh) * W + ww];
      ((float*)xs)[i] = v;
    }
    // stage weights: ws[c][k][o] = w_off[(o*C + cb*CB + c)*9 + k]
    for (int i = tid; i < CB * 9 * OOFF; i += 256) {
      const int o = i % OOFF;
      const int k = (i / OOFF) % 9;
      const int cc = i / (9 * OOFF);
      ((float*)ws)[i] = w_off[((size_t)o * C + cb * CB + cc) * 9 + k];
    }
    __syncthreads();
#pragma unroll
    for (int cc = 0; cc < CB; ++cc) {
#pragma unroll
      for (int k = 0; k < 9; ++k) {
        const float xv = xs[cc][py + k / 3][px + k % 3];
#pragma unroll
        for (int o = 0; o < OOFF; ++o) acc[o] += xv * ws[cc][k][o];
      }
    }
    __syncthreads();
  }
#pragma unroll
  for (int o = 0; o < OOFF; ++o)
    off[(((size_t)b * OOFF + o) * H + h0 + py) * W + w0 + px] = acc[o] + b_off[o];
}

// -------------------------------------------------------------------------
// Kernel 3: deformable conv (torchvision semantics, 1 offset group).
// Thread per pixel, 64 accumulators. Per-kk weight slab [o][c] in LDS so the
// inner product uses float4 (b128) weight reads. Bilinear corner weights are
// pre-multiplied by validity, so clamped addresses are safe.
// grid: (12, 12, 4), 256 threads
// -------------------------------------------------------------------------
__global__ __launch_bounds__(256) void k_deform(const float* __restrict__ xt,
                                                const float* __restrict__ off,
                                                const float* __restrict__ w_conv,
                                                const float* __restrict__ b_conv,
                                                float* __restrict__ y) {
  __shared__ float wk[O * C]; // [o][c] for current kk
  const int w0 = blockIdx.x * 16, h0 = blockIdx.y * 16, b = blockIdx.z;
  const int tid = threadIdx.x;
  const int px = tid & 15, py = tid >> 4;
  const int h = h0 + py, w = w0 + px;

  float acc[O];
#pragma unroll
  for (int o = 0; o < O; ++o) acc[o] = 0.f;

  for (int kk = 0; kk < 9; ++kk) {
    __syncthreads(); // protect previous iteration's wk reads
    for (int i = tid; i < O * C; i += 256) wk[i] = w_conv[(size_t)i * 9 + kk];
    __syncthreads();

    const float dy = off[(((size_t)b * OOFF + 2 * kk) * H + h) * W + w];
    const float dx = off[(((size_t)b * OOFF + 2 * kk + 1) * H + h) * W + w];
    const int ky = kk / 3, kx = kk % 3;
    const float pyf = dy + (float)(ky + h - 1);
    const float pxf = dx + (float)(kx + w - 1);
    const float fy0 = floorf(pyf), fx0 = floorf(pxf);
    const float wy = pyf - fy0, wx = pxf - fx0;
    const int iy0 = (int)fy0, ix0 = (int)fx0;
    const int iy1 = iy0 + 1, ix1 = ix0 + 1;
    const bool vy0 = (iy0 >= 0) && (iy0 < H);
    const bool vy1 = (iy1 >= 0) && (iy1 < H);
    const bool vx0 = (ix0 >= 0) && (ix0 < W);
    const bool vx1 = (ix1 >= 0) && (ix1 < W);
    const float a00 = (vy0 && vx0) ? (1.f - wy) * (1.f - wx) : 0.f;
    const float a01 = (vy0 && vx1) ? (1.f - wy) * wx : 0.f;
    const float a10 = (vy1 && vx0) ? wy * (1.f - wx) : 0.f;
    const float a11 = (vy1 && vx1) ? wy * wx : 0.f;
    const int cy0 = min(max(iy0, 0), H - 1), cy1 = min(max(iy1, 0), H - 1);
    const int cx0 = min(max(ix0, 0), W - 1), cx1 = min(max(ix1, 0), W - 1);
    const float4* p00 = (const float4*)(xt + (((size_t)b * H + cy0) * W + cx0) * C);
    const float4* p01 = (const float4*)(xt + (((size_t)b * H + cy0) * W + cx1) * C);
    const float4* p10 = (const float4*)(xt + (((size_t)b * H + cy1) * W + cx0) * C);
    const float4* p11 = (const float4*)(xt + (((size_t)b * H + cy1) * W + cx1) * C);
    const float4* wkv = (const float4*)wk;

    for (int cq = 0; cq < C / 4; ++cq) {
      const float4 v00 = p00[cq], v01 = p01[cq], v10 = p10[cq], v11 = p11[cq];
      float4 s;
      s.x = v00.x * a00 + v01.x * a01 + v10.x * a10 + v11.x * a11;
      s.y = v00.y * a00 + v01.y * a01 + v10.y * a10 + v11.y * a11;
      s.z = v00.z * a00 + v01.z * a01 + v10.z * a10 + v11.z * a11;
      s.w = v00.w * a00 + v01.w * a01 + v10.w * a10 + v11.w * a11;
#pragma unroll
      for (int o = 0; o < O; ++o) {
        const float4 wv = wkv[o * (C / 4) + cq];
        acc[o] += s.x * wv.x + s.y * wv.y + s.z * wv.z + s.w * wv.w;
      }
    }
  }
#pragma unroll
  for (int o = 0; o < O; ++o)
    y[(((size_t)b * O + o) * H + h) * W + w] = acc[o] + b_conv[o];
}

// -------------------------------------------------------------------------
// Kernel 4: main 3x3 conv (64 -> 64, pad 1) on deform output, writes d_out.
// Register-blocked implicit GEMM: tile 16w x 8h, thread = 4 px x 8 oc.
// x reads: b32 from LDS halo tile; w reads: float4, wave-uniform per
// half-wave (broadcast). ~3 LDS reads per 32 FMAs -> VALU-bound.
// grid: (12, 24, 4), 256 threads
// -------------------------------------------------------------------------
__global__ __launch_bounds__(256) void k_conv_main(const float* __restrict__ in,
                                                   const float* __restrict__ w_conv,
                                                   const float* __restrict__ b_conv,
                                                   float* __restrict__ out) {
  constexpr int CB = 8;
  __shared__ float ys[CB][10][18]; // halo tile for 8h x 16w
  __shared__ float wl[CB][9][O];   // [c][k][o]
  const int w0 = blockIdx.x * 16, h0 = blockIdx.y * 8, b = blockIdx.z;
  const int tid = threadIdx.x;
  const int q = tid & 31, og = tid >> 5; // 32 quads x 8 oc-groups
  const int qx = q & 3, qy = q >> 2;     // quad = 4 consecutive w

  float acc[4][8];
#pragma unroll
  for (int p = 0; p < 4; ++p)
#pragma unroll
    for (int j = 0; j < 8; ++j) acc[p][j] = 0.f;

  for (int cb = 0; cb < C / CB; ++cb) {
    for (int i = tid; i < CB * 10 * 18; i += 256) {
      const int cc = i / 180;
      const int rem = i - cc * 180;
      const int ty = rem / 18, tx = rem - (rem / 18) * 18;
      const int hh = h0 + ty - 1, ww = w0 + tx - 1;
      float v = 0.f;
      if (hh >= 0 && hh < H && ww >= 0 && ww < W)
        v = in[(((size_t)b * C + cb * CB + cc) * H + hh) * W + ww];
      ((float*)ys)[i] = v;
    }
    for (int i = tid; i < CB * 9 * O; i += 256) {
      const int o = i & 63;
      const int k = (i >> 6) % 9;
      const int cc = i / (9 * O);
      ((float*)wl)[i] = w_conv[((size_t)o * C + cb * CB + cc) * 9 + k];
    }
    __syncthreads();
#pragma unroll
    for (int cc = 0; cc < CB; ++cc) {
#pragma unroll
      for (int ky = 0; ky < 3; ++ky) {
        float xv[6];
#pragma unroll
        for (int j = 0; j < 6; ++j) xv[j] = ys[cc][qy + ky][qx * 4 + j];
#pragma unroll
        for (int kx = 0; kx < 3; ++kx) {
          const float4 wv0 = *(const float4*)&wl[cc][ky * 3 + kx][og * 8];
          const float4 wv1 = *(const float4*)&wl[cc][ky * 3 + kx][og * 8 + 4];
#pragma unroll
          for (int p = 0; p < 4; ++p) {
            const float xval = xv[p + kx];
            acc[p][0] += xval * wv0.x;
            acc[p][1] += xval * wv0.y;
            acc[p][2] += xval * wv0.z;
            acc[p][3] += xval * wv0.w;
            acc[p][4] += xval * wv1.x;
            acc[p][5] += xval * wv1.y;
            acc[p][6] += xval * wv1.z;
            acc[p][7] += xval * wv1.w;
          }
        }
      }
    }
    __syncthreads();
  }
#pragma unroll
  for (int j = 0; j < 8; ++j) {
    const int o = og * 8 + j;
    const float bias = b_conv[o];
    float4 v;
    v.x = acc[0][j] + bias;
    v.y = acc[1][j] + bias;
    v.z = acc[2][j] + bias;
    v.w = acc[3][j] + bias;
    *(float4*)&out[(((size_t)b * O + o) * H + h0 + qy) * W + w0 + qx * 4] = v;
  }
}

// -------------------------------------------------------------------------
extern "C" void kernel_launch(void* const* d_in, const int* in_sizes, int n_in,
                              void* d_out, int out_size, void* d_ws, size_t ws_size,
                              hipStream_t stream) {
  const float* x = (const float*)d_in[0];      // [4,64,192,192]
  const float* w_off = (const float*)d_in[1];  // [18,64,3,3]
  const float* b_off = (const float*)d_in[2];  // [18]
  const float* w_conv = (const float*)d_in[3]; // [64,64,3,3]
  const float* b_conv = (const float*)d_in[4]; // [64]
  float* out = (float*)d_out;                  // [4,64,192,192]

  float* ws = (float*)d_ws;
  float* off = ws;                                // B*18*H*W   = 2,654,208 f
  float* xt = off + (size_t)B * OOFF * H * W;     // B*H*W*C    = 9,437,184 f
  float* y = xt + (size_t)B * H * W * C;          // B*C*H*W    = 9,437,184 f

  const dim3 blk(256);
  k_transpose<<<dim3(W / 16, H, B), blk, 0, stream>>>(x, xt);
  k_conv_off<<<dim3(W / 16, H / 16, B), blk, 0, stream>>>(x, w_off, b_off, off);
  k_deform<<<dim3(W / 16, H / 16, B), blk, 0, stream>>>(xt, off, w_conv, b_conv, y);
  k_conv_main<<<dim3(W / 16, H / 8, B), blk, 0, stream>>>(y, w_conv, b_conv, out);
}

// Round 2
// 575.280 us; speedup vs baseline: 1.4099x; 1.4099x over previous
//
#include <hip/hip_runtime.h>

// Problem constants (fixed by setup_inputs)
constexpr int B = 4;
constexpr int C = 64;    // input channels
constexpr int O = 64;    // output channels (main conv)
constexpr int OOFF = 18; // offset channels = 2*3*3
constexpr int H = 192;
constexpr int W = 192;

typedef __attribute__((ext_vector_type(8))) short short8;  // 8 bf16 = 4 VGPR
typedef __attribute__((ext_vector_type(4))) float float4v; // MFMA acc

__device__ inline ushort f2bf(float f) { // round-to-nearest-even bf16
  unsigned u = __float_as_uint(f);
  unsigned r = (u + 0x7fffu + ((u >> 16) & 1u)) >> 16;
  return (ushort)r;
}

// -------------------------------------------------------------------------
// Kernel 0: convert w_conv to bf16 B-fragments for mfma_f32_16x16x32_bf16.
// Layout: wBf[kk][kstep][nt][lane][j], element B[k=c][n=oc]:
//   n = nt*16 + (lane&15), c = kstep*32 + (lane>>4)*8 + j
// -------------------------------------------------------------------------
__global__ __launch_bounds__(256) void k_prep_wB(const float* __restrict__ w_conv,
                                                 ushort* __restrict__ wBf) {
  const int i = blockIdx.x * 256 + threadIdx.x;
  if (i >= 9 * 2 * 4 * 64 * 8) return;
  const int j = i & 7;
  const int lane = (i >> 3) & 63;
  const int nt = (i >> 9) & 3;
  const int kstep = (i >> 11) & 1;
  const int kk = i >> 12;
  const int n = nt * 16 + (lane & 15);
  const int c = kstep * 32 + ((lane >> 4) & 3) * 8 + j;
  wBf[i] = f2bf(w_conv[((size_t)n * C + c) * 9 + kk]);
}

// -------------------------------------------------------------------------
// Kernel 1: transpose x [B,C,H,W] -> xt [B,H,W,C] (channels-last).
// -------------------------------------------------------------------------
__global__ __launch_bounds__(256) void k_transpose(const float* __restrict__ x,
                                                   float* __restrict__ xt) {
  __shared__ float tile[64][17];
  const int w0 = blockIdx.x * 16;
  const int h = blockIdx.y;
  const int b = blockIdx.z;
  const int tid = threadIdx.x;

  const int wl = tid & 15;
  const int c0 = tid >> 4;
#pragma unroll
  for (int r = 0; r < 4; ++r) {
    const int c = c0 + r * 16;
    tile[c][wl] = x[(((size_t)b * C + c) * H + h) * W + w0 + wl];
  }
  __syncthreads();
  const int c = tid & 63;
  const int qq = tid >> 6;
#pragma unroll
  for (int r = 0; r < 4; ++r) {
    const int wq = qq + r * 4;
    xt[(((size_t)b * H + h) * W + w0 + wq) * C + c] = tile[c][wq];
  }
}

// -------------------------------------------------------------------------
// Kernel 2: offset conv (3x3, C=64 -> 18, pad 1). fp32 (accuracy-critical).
// -------------------------------------------------------------------------
__global__ __launch_bounds__(256) void k_conv_off(const float* __restrict__ x,
                                                  const float* __restrict__ w_off,
                                                  const float* __restrict__ b_off,
                                                  float* __restrict__ off) {
  constexpr int CB = 8;
  __shared__ float xs[CB][18][18];
  __shared__ float ws[CB][9][OOFF];
  const int w0 = blockIdx.x * 16, h0 = blockIdx.y * 16, b = blockIdx.z;
  const int tid = threadIdx.x;
  const int px = tid & 15, py = tid >> 4;

  float acc[OOFF];
#pragma unroll
  for (int o = 0; o < OOFF; ++o) acc[o] = 0.f;

  for (int cb = 0; cb < C / CB; ++cb) {
    for (int i = tid; i < CB * 18 * 18; i += 256) {
      const int cc = i / 324;
      const int rem = i - cc * 324;
      const int ty = rem / 18, tx = rem - (rem / 18) * 18;
      const int hh = h0 + ty - 1, ww = w0 + tx - 1;
      float v = 0.f;
      if (hh >= 0 && hh < H && ww >= 0 && ww < W)
        v = x[(((size_t)b * C + cb * CB + cc) * H + hh) * W + ww];
      ((float*)xs)[i] = v;
    }
    for (int i = tid; i < CB * 9 * OOFF; i += 256) {
      const int o = i % OOFF;
      const int k = (i / OOFF) % 9;
      const int cc = i / (9 * OOFF);
      ((float*)ws)[i] = w_off[((size_t)o * C + cb * CB + cc) * 9 + k];
    }
    __syncthreads();
#pragma unroll
    for (int cc = 0; cc < CB; ++cc) {
#pragma unroll
      for (int k = 0; k < 9; ++k) {
        const float xv = xs[cc][py + k / 3][px + k % 3];
#pragma unroll
        for (int o = 0; o < OOFF; ++o) acc[o] += xv * ws[cc][k][o];
      }
    }
    __syncthreads();
  }
#pragma unroll
  for (int o = 0; o < OOFF; ++o)
    off[(((size_t)b * OOFF + o) * H + h0 + py) * W + w0 + px] = acc[o] + b_off[o];
}

// -------------------------------------------------------------------------
// Kernel 3: deformable conv via bf16 MFMA.
// Block = 16w x 8h px tile (M=128), 256 threads = 4 waves.
// Wave w computes m-tiles {2w,2w+1} x all 4 n-tiles (64 oc).
// Per kk tap: fp32 bilinear gather -> bf16 A-fragments in LDS -> 2 k-steps
// of mfma_f32_16x16x32_bf16 against pre-built global B-fragments.
// A-frag layout (m120): A[m=lane&15][k=(lane>>4)*8+j]
// C/D layout (m89):     m=(lane>>4)*4+reg, n=lane&15  -> float4 row stores.
// -------------------------------------------------------------------------
__global__ __launch_bounds__(256, 3) void k_deform_mfma(
    const float* __restrict__ xt, const float* __restrict__ off,
    const ushort* __restrict__ wBf, const float* __restrict__ b_conv,
    float* __restrict__ y) {
  __shared__ ushort sA[2][8][64][8]; // [kstep][m_tile][lane][j] = 16 KB

  // XCD-locality swizzle: xcd = bid&7 owns half an image (rows 0..95 or 96..191)
  const int bid = blockIdx.x;
  const int xcd = bid & 7;
  const int s = bid >> 3; // 0..143
  const int b = xcd >> 1;
  const int half = xcd & 1;
  const int th = half * 12 + s / 12; // 0..23 (8-row tiles)
  const int tw = s % 12;             // 0..11 (16-col tiles)
  const int h0 = th * 8, w0 = tw * 16;

  const int tid = threadIdx.x;
  const int wave = tid >> 6, lane = tid & 63;

  // gather assignment: thread = (px p, 32-channel half)
  const int p = tid >> 1;          // 0..127
  const int kstep = tid & 1;       // which 32-c half
  const int py_ = p >> 4, x_ = p & 15;
  const int h = h0 + py_, w = w0 + x_;

  float4v acc[2][4];
#pragma unroll
  for (int m = 0; m < 2; ++m)
#pragma unroll
    for (int n = 0; n < 4; ++n) acc[m][n] = (float4v){0.f, 0.f, 0.f, 0.f};

#pragma unroll 1
  for (int kk = 0; kk < 9; ++kk) {
    // ---- fp32 bilinear gather of 32 channels for px p ----
    const float dy = off[(((size_t)b * OOFF + 2 * kk) * H + h) * W + w];
    const float dx = off[(((size_t)b * OOFF + 2 * kk + 1) * H + h) * W + w];
    const int ky = kk / 3, kx = kk % 3;
    const float pyf = dy + (float)(ky + h - 1);
    const float pxf = dx + (float)(kx + w - 1);
    const float fy0 = floorf(pyf), fx0 = floorf(pxf);
    const float wy = pyf - fy0, wx = pxf - fx0;
    const int iy0 = (int)fy0, ix0 = (int)fx0;
    const int iy1 = iy0 + 1, ix1 = ix0 + 1;
    const bool vy0 = (iy0 >= 0) && (iy0 < H);
    const bool vy1 = (iy1 >= 0) && (iy1 < H);
    const bool vx0 = (ix0 >= 0) && (ix0 < W);
    const bool vx1 = (ix1 >= 0) && (ix1 < W);
    const float a00 = (vy0 && vx0) ? (1.f - wy) * (1.f - wx) : 0.f;
    const float a01 = (vy0 && vx1) ? (1.f - wy) * wx : 0.f;
    const float a10 = (vy1 && vx0) ? wy * (1.f - wx) : 0.f;
    const float a11 = (vy1 && vx1) ? wy * wx : 0.f;
    const int cy0 = min(max(iy0, 0), H - 1), cy1 = min(max(iy1, 0), H - 1);
    const int cx0 = min(max(ix0, 0), W - 1), cx1 = min(max(ix1, 0), W - 1);
    const float4* p00 = (const float4*)(xt + (((size_t)b * H + cy0) * W + cx0) * C);
    const float4* p01 = (const float4*)(xt + (((size_t)b * H + cy0) * W + cx1) * C);
    const float4* p10 = (const float4*)(xt + (((size_t)b * H + cy1) * W + cx0) * C);
    const float4* p11 = (const float4*)(xt + (((size_t)b * H + cy1) * W + cx1) * C);

    uint4 pk[4];
#pragma unroll
    for (int chunk = 0; chunk < 4; ++chunk) {
      const int qb = kstep * 8 + chunk * 2; // float4 index into 64-c row
      float4 sv[2];
#pragma unroll
      for (int q = 0; q < 2; ++q) {
        const float4 v00 = p00[qb + q], v01 = p01[qb + q];
        const float4 v10 = p10[qb + q], v11 = p11[qb + q];
        sv[q].x = v00.x * a00 + v01.x * a01 + v10.x * a10 + v11.x * a11;
        sv[q].y = v00.y * a00 + v01.y * a01 + v10.y * a10 + v11.y * a11;
        sv[q].z = v00.z * a00 + v01.z * a01 + v10.z * a10 + v11.z * a11;
        sv[q].w = v00.w * a00 + v01.w * a01 + v10.w * a10 + v11.w * a11;
      }
      pk[chunk].x = (uint)f2bf(sv[0].x) | ((uint)f2bf(sv[0].y) << 16);
      pk[chunk].y = (uint)f2bf(sv[0].z) | ((uint)f2bf(sv[0].w) << 16);
      pk[chunk].z = (uint)f2bf(sv[1].x) | ((uint)f2bf(sv[1].y) << 16);
      pk[chunk].w = (uint)f2bf(sv[1].z) | ((uint)f2bf(sv[1].w) << 16);
    }

    __syncthreads(); // prior MFMA reads of sA complete
#pragma unroll
    for (int chunk = 0; chunk < 4; ++chunk) {
      // element (p, c = kstep*32 + chunk*8 + j) -> quad = chunk, lane = x_|(chunk<<4)
      *(uint4*)&sA[kstep][py_][x_ | (chunk << 4)][0] = pk[chunk];
    }
    __syncthreads();

    // ---- MFMA: 2 k-steps x (2 m-tiles x 4 n-tiles) ----
#pragma unroll
    for (int ks = 0; ks < 2; ++ks) {
      const short8 a0 = *(const short8*)&sA[ks][2 * wave][lane][0];
      const short8 a1 = *(const short8*)&sA[ks][2 * wave + 1][lane][0];
#pragma unroll
      for (int nt = 0; nt < 4; ++nt) {
        const short8 bb = *(const short8*)&wBf[((((size_t)kk * 2 + ks) * 4 + nt) * 64 + lane) * 8];
        acc[0][nt] = __builtin_amdgcn_mfma_f32_16x16x32_bf16(a0, bb, acc[0][nt], 0, 0, 0);
        acc[1][nt] = __builtin_amdgcn_mfma_f32_16x16x32_bf16(a1, bb, acc[1][nt], 0, 0, 0);
      }
    }
  }

  // ---- epilogue: lane's 4 regs = 4 consecutive x -> float4 stores ----
  const int quad = lane >> 4;
#pragma unroll
  for (int mi = 0; mi < 2; ++mi) {
    const int mt = 2 * wave + mi; // row within tile = h0 + mt
#pragma unroll
    for (int nt = 0; nt < 4; ++nt) {
      const int oc = nt * 16 + (lane & 15);
      const float bias = b_conv[oc];
      float4 v;
      v.x = acc[mi][nt][0] + bias;
      v.y = acc[mi][nt][1] + bias;
      v.z = acc[mi][nt][2] + bias;
      v.w = acc[mi][nt][3] + bias;
      *(float4*)&y[(((size_t)b * O + oc) * H + h0 + mt) * W + w0 + quad * 4] = v;
    }
  }
}

// -------------------------------------------------------------------------
// Kernel 4: main 3x3 conv (64 -> 64, pad 1), fp32 register-blocked.
// -------------------------------------------------------------------------
__global__ __launch_bounds__(256) void k_conv_main(const float* __restrict__ in,
                                                   const float* __restrict__ w_conv,
                                                   const float* __restrict__ b_conv,
                                                   float* __restrict__ out) {
  constexpr int CB = 8;
  __shared__ float ys[CB][10][18];
  __shared__ float wl[CB][9][O];
  const int w0 = blockIdx.x * 16, h0 = blockIdx.y * 8, b = blockIdx.z;
  const int tid = threadIdx.x;
  const int q = tid & 31, og = tid >> 5;
  const int qx = q & 3, qy = q >> 2;

  float acc[4][8];
#pragma unroll
  for (int p = 0; p < 4; ++p)
#pragma unroll
    for (int j = 0; j < 8; ++j) acc[p][j] = 0.f;

  for (int cb = 0; cb < C / CB; ++cb) {
    for (int i = tid; i < CB * 10 * 18; i += 256) {
      const int cc = i / 180;
      const int rem = i - cc * 180;
      const int ty = rem / 18, tx = rem - (rem / 18) * 18;
      const int hh = h0 + ty - 1, ww = w0 + tx - 1;
      float v = 0.f;
      if (hh >= 0 && hh < H && ww >= 0 && ww < W)
        v = in[(((size_t)b * C + cb * CB + cc) * H + hh) * W + ww];
      ((float*)ys)[i] = v;
    }
    for (int i = tid; i < CB * 9 * O; i += 256) {
      const int o = i & 63;
      const int k = (i >> 6) % 9;
      const int cc = i / (9 * O);
      ((float*)wl)[i] = w_conv[((size_t)o * C + cb * CB + cc) * 9 + k];
    }
    __syncthreads();
#pragma unroll
    for (int cc = 0; cc < CB; ++cc) {
#pragma unroll
      for (int ky = 0; ky < 3; ++ky) {
        float xv[6];
#pragma unroll
        for (int j = 0; j < 6; ++j) xv[j] = ys[cc][qy + ky][qx * 4 + j];
#pragma unroll
        for (int kx = 0; kx < 3; ++kx) {
          const float4 wv0 = *(const float4*)&wl[cc][ky * 3 + kx][og * 8];
          const float4 wv1 = *(const float4*)&wl[cc][ky * 3 + kx][og * 8 + 4];
#pragma unroll
          for (int p = 0; p < 4; ++p) {
            const float xval = xv[p + kx];
            acc[p][0] += xval * wv0.x;
            acc[p][1] += xval * wv0.y;
            acc[p][2] += xval * wv0.z;
            acc[p][3] += xval * wv0.w;
            acc[p][4] += xval * wv1.x;
            acc[p][5] += xval * wv1.y;
            acc[p][6] += xval * wv1.z;
            acc[p][7] += xval * wv1.w;
          }
        }
      }
    }
    __syncthreads();
  }
#pragma unroll
  for (int j = 0; j < 8; ++j) {
    const int o = og * 8 + j;
    const float bias = b_conv[o];
    float4 v;
    v.x = acc[0][j] + bias;
    v.y = acc[1][j] + bias;
    v.z = acc[2][j] + bias;
    v.w = acc[3][j] + bias;
    *(float4*)&out[(((size_t)b * O + o) * H + h0 + qy) * W + w0 + qx * 4] = v;
  }
}

// -------------------------------------------------------------------------
extern "C" void kernel_launch(void* const* d_in, const int* in_sizes, int n_in,
                              void* d_out, int out_size, void* d_ws, size_t ws_size,
                              hipStream_t stream) {
  const float* x = (const float*)d_in[0];
  const float* w_off = (const float*)d_in[1];
  const float* b_off = (const float*)d_in[2];
  const float* w_conv = (const float*)d_in[3];
  const float* b_conv = (const float*)d_in[4];
  float* out = (float*)d_out;

  float* ws = (float*)d_ws;
  float* off = ws;                            // B*18*H*W
  float* xt = off + (size_t)B * OOFF * H * W; // B*H*W*C
  float* y = xt + (size_t)B * H * W * C;      // B*C*H*W
  ushort* wBf = (ushort*)(y + (size_t)B * C * H * W); // 36864 bf16

  const dim3 blk(256);
  k_prep_wB<<<dim3(144), blk, 0, stream>>>(w_conv, wBf);
  k_transpose<<<dim3(W / 16, H, B), blk, 0, stream>>>(x, xt);
  k_conv_off<<<dim3(W / 16, H / 16, B), blk, 0, stream>>>(x, w_off, b_off, off);
  k_deform_mfma<<<dim3(1152), blk, 0, stream>>>(xt, off, wBf, b_conv, y);
  k_conv_main<<<dim3(W / 16, H / 8, B), blk, 0, stream>>>(y, w_conv, b_conv, out);
}

// Round 3
// 417.865 us; speedup vs baseline: 1.9410x; 1.3767x over previous
//
#include <hip/hip_runtime.h>

// Problem constants (fixed by setup_inputs)
constexpr int B = 4;
constexpr int C = 64;    // input channels
constexpr int O = 64;    // output channels (main conv)
constexpr int OOFF = 18; // offset channels = 2*3*3
constexpr int H = 192;
constexpr int W = 192;

typedef __attribute__((ext_vector_type(8))) short short8;  // 8 bf16 = 4 VGPR
typedef __attribute__((ext_vector_type(4))) float float4v; // MFMA acc

__device__ inline ushort f2bf(float f) { // round-to-nearest-even bf16
  unsigned u = __float_as_uint(f);
  unsigned r = (u + 0x7fffu + ((u >> 16) & 1u)) >> 16;
  return (ushort)r;
}

// -------------------------------------------------------------------------
// Kernel 0: convert w_conv to bf16 B-fragments for mfma_f32_16x16x32_bf16.
// PERMUTED n-mapping so C/D cols give channel-adjacent values per lane:
//   n(oc) = nt + 4*(lane&15),  k(c) = kstep*32 + (lane>>4)*8 + j
// Layout: wBf[kk][kstep][nt][lane][j].
// -------------------------------------------------------------------------
__global__ __launch_bounds__(256) void k_prep_wB(const float* __restrict__ w_conv,
                                                 ushort* __restrict__ wBf) {
  const int i = blockIdx.x * 256 + threadIdx.x;
  if (i >= 9 * 2 * 4 * 64 * 8) return;
  const int j = i & 7;
  const int lane = (i >> 3) & 63;
  const int nt = (i >> 9) & 3;
  const int kstep = (i >> 11) & 1;
  const int kk = i >> 12;
  const int n = nt + 4 * (lane & 15); // permuted
  const int c = kstep * 32 + ((lane >> 4) & 3) * 8 + j;
  wBf[i] = f2bf(w_conv[((size_t)n * C + c) * 9 + kk]);
}

// -------------------------------------------------------------------------
// Kernel 1: transpose x [B,C,H,W] -> xt [B,H,W,C] fp32 (deform gather input).
// -------------------------------------------------------------------------
__global__ __launch_bounds__(256) void k_transpose(const float* __restrict__ x,
                                                   float* __restrict__ xt) {
  __shared__ float tile[64][17];
  const int w0 = blockIdx.x * 16;
  const int h = blockIdx.y;
  const int b = blockIdx.z;
  const int tid = threadIdx.x;

  const int wl = tid & 15;
  const int c0 = tid >> 4;
#pragma unroll
  for (int r = 0; r < 4; ++r) {
    const int c = c0 + r * 16;
    tile[c][wl] = x[(((size_t)b * C + c) * H + h) * W + w0 + wl];
  }
  __syncthreads();
  const int c = tid & 63;
  const int qq = tid >> 6;
#pragma unroll
  for (int r = 0; r < 4; ++r) {
    const int wq = qq + r * 4;
    xt[(((size_t)b * H + h) * W + w0 + wq) * C + c] = tile[c][wq];
  }
}

// -------------------------------------------------------------------------
// Kernel 2: offset conv (3x3, C=64 -> 18, pad 1). fp32 (accuracy-critical).
// -------------------------------------------------------------------------
__global__ __launch_bounds__(256) void k_conv_off(const float* __restrict__ x,
                                                  const float* __restrict__ w_off,
                                                  const float* __restrict__ b_off,
                                                  float* __restrict__ off) {
  constexpr int CB = 8;
  __shared__ float xs[CB][18][18];
  __shared__ float ws[CB][9][OOFF];
  const int w0 = blockIdx.x * 16, h0 = blockIdx.y * 16, b = blockIdx.z;
  const int tid = threadIdx.x;
  const int px = tid & 15, py = tid >> 4;

  float acc[OOFF];
#pragma unroll
  for (int o = 0; o < OOFF; ++o) acc[o] = 0.f;

  for (int cb = 0; cb < C / CB; ++cb) {
    for (int i = tid; i < CB * 18 * 18; i += 256) {
      const int cc = i / 324;
      const int rem = i - cc * 324;
      const int ty = rem / 18, tx = rem - (rem / 18) * 18;
      const int hh = h0 + ty - 1, ww = w0 + tx - 1;
      float v = 0.f;
      if (hh >= 0 && hh < H && ww >= 0 && ww < W)
        v = x[(((size_t)b * C + cb * CB + cc) * H + hh) * W + ww];
      ((float*)xs)[i] = v;
    }
    for (int i = tid; i < CB * 9 * OOFF; i += 256) {
      const int o = i % OOFF;
      const int k = (i / OOFF) % 9;
      const int cc = i / (9 * OOFF);
      ((float*)ws)[i] = w_off[((size_t)o * C + cb * CB + cc) * 9 + k];
    }
    __syncthreads();
#pragma unroll
    for (int cc = 0; cc < CB; ++cc) {
#pragma unroll
      for (int k = 0; k < 9; ++k) {
        const float xv = xs[cc][py + k / 3][px + k % 3];
#pragma unroll
        for (int o = 0; o < OOFF; ++o) acc[o] += xv * ws[cc][k][o];
      }
    }
    __syncthreads();
  }
#pragma unroll
  for (int o = 0; o < OOFF; ++o)
    off[(((size_t)b * OOFF + o) * H + h0 + py) * W + w0 + px] = acc[o] + b_off[o];
}

// -------------------------------------------------------------------------
// Kernel 3: deformable conv via bf16 MFMA.
// Same GEMM structure as R1, but epilogue writes bf16 channels-last
// yt[B,H,W,C] (y + bias) with coalesced uint2 stores using the permuted
// oc = nt + 4*(lane&15) mapping. No fp32 y buffer.
// -------------------------------------------------------------------------
__global__ __launch_bounds__(256, 3) void k_deform_mfma(
    const float* __restrict__ xt, const float* __restrict__ off,
    const ushort* __restrict__ wBf, const float* __restrict__ b_conv,
    ushort* __restrict__ yt) {
  __shared__ ushort sA[2][8][64][8]; // [kstep][m_tile][lane][j] = 16 KB

  // XCD-locality swizzle
  const int bid = blockIdx.x;
  const int xcd = bid & 7;
  const int s = bid >> 3;
  const int b = xcd >> 1;
  const int half = xcd & 1;
  const int th = half * 12 + s / 12;
  const int tw = s % 12;
  const int h0 = th * 8, w0 = tw * 16;

  const int tid = threadIdx.x;
  const int wave = tid >> 6, lane = tid & 63;

  const int p = tid >> 1;
  const int kstep = tid & 1;
  const int py_ = p >> 4, x_ = p & 15;
  const int h = h0 + py_, w = w0 + x_;

  float4v acc[2][4];
#pragma unroll
  for (int m = 0; m < 2; ++m)
#pragma unroll
    for (int n = 0; n < 4; ++n) acc[m][n] = (float4v){0.f, 0.f, 0.f, 0.f};

#pragma unroll 1
  for (int kk = 0; kk < 9; ++kk) {
    const float dy = off[(((size_t)b * OOFF + 2 * kk) * H + h) * W + w];
    const float dx = off[(((size_t)b * OOFF + 2 * kk + 1) * H + h) * W + w];
    const int ky = kk / 3, kx = kk % 3;
    const float pyf = dy + (float)(ky + h - 1);
    const float pxf = dx + (float)(kx + w - 1);
    const float fy0 = floorf(pyf), fx0 = floorf(pxf);
    const float wy = pyf - fy0, wx = pxf - fx0;
    const int iy0 = (int)fy0, ix0 = (int)fx0;
    const int iy1 = iy0 + 1, ix1 = ix0 + 1;
    const bool vy0 = (iy0 >= 0) && (iy0 < H);
    const bool vy1 = (iy1 >= 0) && (iy1 < H);
    const bool vx0 = (ix0 >= 0) && (ix0 < W);
    const bool vx1 = (ix1 >= 0) && (ix1 < W);
    const float a00 = (vy0 && vx0) ? (1.f - wy) * (1.f - wx) : 0.f;
    const float a01 = (vy0 && vx1) ? (1.f - wy) * wx : 0.f;
    const float a10 = (vy1 && vx0) ? wy * (1.f - wx) : 0.f;
    const float a11 = (vy1 && vx1) ? wy * wx : 0.f;
    const int cy0 = min(max(iy0, 0), H - 1), cy1 = min(max(iy1, 0), H - 1);
    const int cx0 = min(max(ix0, 0), W - 1), cx1 = min(max(ix1, 0), W - 1);
    const float4* p00 = (const float4*)(xt + (((size_t)b * H + cy0) * W + cx0) * C);
    const float4* p01 = (const float4*)(xt + (((size_t)b * H + cy0) * W + cx1) * C);
    const float4* p10 = (const float4*)(xt + (((size_t)b * H + cy1) * W + cx0) * C);
    const float4* p11 = (const float4*)(xt + (((size_t)b * H + cy1) * W + cx1) * C);

    uint4 pk[4];
#pragma unroll
    for (int chunk = 0; chunk < 4; ++chunk) {
      const int qb = kstep * 8 + chunk * 2;
      float4 sv[2];
#pragma unroll
      for (int q = 0; q < 2; ++q) {
        const float4 v00 = p00[qb + q], v01 = p01[qb + q];
        const float4 v10 = p10[qb + q], v11 = p11[qb + q];
        sv[q].x = v00.x * a00 + v01.x * a01 + v10.x * a10 + v11.x * a11;
        sv[q].y = v00.y * a00 + v01.y * a01 + v10.y * a10 + v11.y * a11;
        sv[q].z = v00.z * a00 + v01.z * a01 + v10.z * a10 + v11.z * a11;
        sv[q].w = v00.w * a00 + v01.w * a01 + v10.w * a10 + v11.w * a11;
      }
      pk[chunk].x = (uint)f2bf(sv[0].x) | ((uint)f2bf(sv[0].y) << 16);
      pk[chunk].y = (uint)f2bf(sv[0].z) | ((uint)f2bf(sv[0].w) << 16);
      pk[chunk].z = (uint)f2bf(sv[1].x) | ((uint)f2bf(sv[1].y) << 16);
      pk[chunk].w = (uint)f2bf(sv[1].z) | ((uint)f2bf(sv[1].w) << 16);
    }

    __syncthreads();
#pragma unroll
    for (int chunk = 0; chunk < 4; ++chunk) {
      *(uint4*)&sA[kstep][py_][x_ | (chunk << 4)][0] = pk[chunk];
    }
    __syncthreads();

#pragma unroll
    for (int ks = 0; ks < 2; ++ks) {
      const short8 a0 = *(const short8*)&sA[ks][2 * wave][lane][0];
      const short8 a1 = *(const short8*)&sA[ks][2 * wave + 1][lane][0];
#pragma unroll
      for (int nt = 0; nt < 4; ++nt) {
        const short8 bb = *(const short8*)&wBf[((((size_t)kk * 2 + ks) * 4 + nt) * 64 + lane) * 8];
        acc[0][nt] = __builtin_amdgcn_mfma_f32_16x16x32_bf16(a0, bb, acc[0][nt], 0, 0, 0);
        acc[1][nt] = __builtin_amdgcn_mfma_f32_16x16x32_bf16(a1, bb, acc[1][nt], 0, 0, 0);
      }
    }
  }

  // ---- epilogue: yt[b][h][w][c] bf16, c base = 4*(lane&15), packed uint2 ----
  const int quad = lane >> 4;
  const int c16 = lane & 15;
  float bias[4];
#pragma unroll
  for (int nt = 0; nt < 4; ++nt) bias[nt] = b_conv[4 * c16 + nt];
#pragma unroll
  for (int mi = 0; mi < 2; ++mi) {
    const int hrow = h0 + 2 * wave + mi;
#pragma unroll
    for (int r = 0; r < 4; ++r) {
      const int wcol = w0 + quad * 4 + r;
      uint2 u;
      u.x = (uint)f2bf(acc[mi][0][r] + bias[0]) | ((uint)f2bf(acc[mi][1][r] + bias[1]) << 16);
      u.y = (uint)f2bf(acc[mi][2][r] + bias[2]) | ((uint)f2bf(acc[mi][3][r] + bias[3]) << 16);
      *(uint2*)&yt[(((size_t)b * H + hrow) * W + wcol) * C + 4 * c16] = u;
    }
  }
}

// -------------------------------------------------------------------------
// Kernel 4: main 3x3 conv via bf16 MFMA, LDS-free implicit GEMM.
// A-fragments load DIRECTLY from channels-last yt: lane supplies
// A[m=lane&15][k=quad*8+j] = yt[b][h0+mt+ky-1][w0+(lane&15)+kx-1][ks*32+quad*8].
// Wave = 4 image rows (4 m-tiles) x 64 oc; block = 4 waves = 16 rows.
// grid: (12, 12, 4), 256 threads. No LDS, no syncthreads.
// -------------------------------------------------------------------------
__global__ __launch_bounds__(256) void k_conv_main_mfma(
    const ushort* __restrict__ yt, const ushort* __restrict__ wBf,
    const float* __restrict__ b_conv, float* __restrict__ out) {
  const int w0 = blockIdx.x * 16;
  const int b = blockIdx.z;
  const int tid = threadIdx.x;
  const int wave = tid >> 6, lane = tid & 63;
  const int col = lane & 15, quad = lane >> 4;
  const int h0 = blockIdx.y * 16 + wave * 4;

  float4v acc[4][4];
#pragma unroll
  for (int mt = 0; mt < 4; ++mt)
#pragma unroll
    for (int nt = 0; nt < 4; ++nt) acc[mt][nt] = (float4v){0.f, 0.f, 0.f, 0.f};

#pragma unroll 1
  for (int kk = 0; kk < 9; ++kk) {
    const int ky = kk / 3, kx = kk % 3;
    const int ww = w0 + col + kx - 1;
    const bool wok = (unsigned)ww < (unsigned)W;
    const int wwc = min(max(ww, 0), W - 1);

    short8 bfr[2][4];
#pragma unroll
    for (int ks = 0; ks < 2; ++ks)
#pragma unroll
      for (int nt = 0; nt < 4; ++nt)
        bfr[ks][nt] = *(const short8*)&wBf[((((size_t)kk * 2 + ks) * 4 + nt) * 64 + lane) * 8];

    short8 afr[4][2];
#pragma unroll
    for (int mt = 0; mt < 4; ++mt) {
      const int hh = h0 + mt + ky - 1;
      const bool ok = wok && ((unsigned)hh < (unsigned)H);
      const int hhc = min(max(hh, 0), H - 1);
      const ushort* pa = yt + (((size_t)b * H + hhc) * W + wwc) * C + quad * 8;
#pragma unroll
      for (int ks = 0; ks < 2; ++ks) {
        short8 v = (short8)0;
        if (ok) v = *(const short8*)(pa + ks * 32);
        afr[mt][ks] = v;
      }
    }
#pragma unroll
    for (int ks = 0; ks < 2; ++ks)
#pragma unroll
      for (int mt = 0; mt < 4; ++mt)
#pragma unroll
        for (int nt = 0; nt < 4; ++nt)
          acc[mt][nt] = __builtin_amdgcn_mfma_f32_16x16x32_bf16(afr[mt][ks], bfr[ks][nt],
                                                                acc[mt][nt], 0, 0, 0);
  }

  float bias[4];
#pragma unroll
  for (int nt = 0; nt < 4; ++nt) bias[nt] = b_conv[4 * col + nt];
#pragma unroll
  for (int mt = 0; mt < 4; ++mt) {
    const int h = h0 + mt;
#pragma unroll
    for (int nt = 0; nt < 4; ++nt) {
      const int oc = 4 * col + nt; // permuted C/D col -> oc
      float4 v;
      v.x = acc[mt][nt][0] + bias[nt];
      v.y = acc[mt][nt][1] + bias[nt];
      v.z = acc[mt][nt][2] + bias[nt];
      v.w = acc[mt][nt][3] + bias[nt];
      *(float4*)&out[(((size_t)b * O + oc) * H + h) * W + w0 + quad * 4] = v;
    }
  }
}

// -------------------------------------------------------------------------
extern "C" void kernel_launch(void* const* d_in, const int* in_sizes, int n_in,
                              void* d_out, int out_size, void* d_ws, size_t ws_size,
                              hipStream_t stream) {
  const float* x = (const float*)d_in[0];
  const float* w_off = (const float*)d_in[1];
  const float* b_off = (const float*)d_in[2];
  const float* w_conv = (const float*)d_in[3];
  const float* b_conv = (const float*)d_in[4];
  float* out = (float*)d_out;

  float* ws = (float*)d_ws;
  float* off = ws;                            // B*18*H*W floats
  float* xt = off + (size_t)B * OOFF * H * W; // B*H*W*C floats
  ushort* yt = (ushort*)(xt + (size_t)B * H * W * C); // B*H*W*C bf16
  ushort* wBf = yt + (size_t)B * H * W * C;           // 36864 bf16

  const dim3 blk(256);
  k_prep_wB<<<dim3(144), blk, 0, stream>>>(w_conv, wBf);
  k_transpose<<<dim3(W / 16, H, B), blk, 0, stream>>>(x, xt);
  k_conv_off<<<dim3(W / 16, H / 16, B), blk, 0, stream>>>(x, w_off, b_off, off);
  k_deform_mfma<<<dim3(1152), blk, 0, stream>>>(xt, off, wBf, b_conv, yt);
  k_conv_main_mfma<<<dim3(W / 16, H / 16, B), blk, 0, stream>>>(yt, wBf, b_conv, out);
}

// Round 4
// 224.005 us; speedup vs baseline: 3.6208x; 1.8654x over previous
//
#include <hip/hip_runtime.h>

// Problem constants (fixed by setup_inputs)
constexpr int B = 4;
constexpr int C = 64;    // input channels
constexpr int O = 64;    // output channels (main conv)
constexpr int OOFF = 18; // offset channels = 2*3*3
constexpr int H = 192;
constexpr int W = 192;

typedef __attribute__((ext_vector_type(8))) short short8;  // 8 bf16 = 4 VGPR
typedef __attribute__((ext_vector_type(4))) float float4v; // MFMA acc

__device__ inline ushort f2bf(float f) { // round-to-nearest-even bf16
  unsigned u = __float_as_uint(f);
  unsigned r = (u + 0x7fffu + ((u >> 16) & 1u)) >> 16;
  return (ushort)r;
}

// -------------------------------------------------------------------------
// Kernel 0a: w_conv -> bf16 B-fragments, PERMUTED n-map (oc = nt + 4*col).
// wBf[kk][ks][nt][lane][j]; k(c) = ks*32 + quad*8 + j.
// -------------------------------------------------------------------------
__global__ __launch_bounds__(256) void k_prep_wB(const float* __restrict__ w_conv,
                                                 ushort* __restrict__ wBf) {
  const int i = blockIdx.x * 256 + threadIdx.x;
  if (i >= 9 * 2 * 4 * 64 * 8) return;
  const int j = i & 7;
  const int lane = (i >> 3) & 63;
  const int nt = (i >> 9) & 3;
  const int kstep = (i >> 11) & 1;
  const int kk = i >> 12;
  const int n = nt + 4 * (lane & 15); // permuted
  const int c = kstep * 32 + ((lane >> 4) & 3) * 8 + j;
  wBf[i] = f2bf(w_conv[((size_t)n * C + c) * 9 + kk]);
}

// -------------------------------------------------------------------------
// Kernel 0b: w_off -> bf16 B-fragments, PLAIN n-map (o = nt*16 + col),
// N padded 18->32 with zeros. wOf[kk][ks][nt(2)][lane][j].
// -------------------------------------------------------------------------
__global__ __launch_bounds__(256) void k_prep_wOff(const float* __restrict__ w_off,
                                                   ushort* __restrict__ wOf) {
  const int i = blockIdx.x * 256 + threadIdx.x;
  if (i >= 9 * 2 * 2 * 64 * 8) return;
  const int j = i & 7;
  const int lane = (i >> 3) & 63;
  const int nt = (i >> 9) & 1;
  const int ks = (i >> 10) & 1;
  const int kk = i >> 11;
  const int n = nt * 16 + (lane & 15);
  const int c = ks * 32 + ((lane >> 4) & 3) * 8 + j;
  wOf[i] = (n < OOFF) ? f2bf(w_off[((size_t)n * C + c) * 9 + kk]) : (ushort)0;
}

// -------------------------------------------------------------------------
// Kernel 1: transpose x [B,C,H,W] fp32 -> xtb [B,H,W,C] bf16.
// -------------------------------------------------------------------------
__global__ __launch_bounds__(256) void k_transpose_bf(const float* __restrict__ x,
                                                      ushort* __restrict__ xtb) {
  __shared__ float tile[64][17];
  const int w0 = blockIdx.x * 16;
  const int h = blockIdx.y;
  const int b = blockIdx.z;
  const int tid = threadIdx.x;

  const int wl = tid & 15;
  const int c0 = tid >> 4;
#pragma unroll
  for (int r = 0; r < 4; ++r) {
    const int c = c0 + r * 16;
    tile[c][wl] = x[(((size_t)b * C + c) * H + h) * W + w0 + wl];
  }
  __syncthreads();
  const int c = tid & 63;
  const int qq = tid >> 6;
#pragma unroll
  for (int r = 0; r < 4; ++r) {
    const int wq = qq + r * 4;
    xtb[(((size_t)b * H + h) * W + w0 + wq) * C + c] = f2bf(tile[c][wq]);
  }
}

// -------------------------------------------------------------------------
// Kernel 2: offset conv via bf16 MFMA, LDS-free (conv_main pattern).
// Output offp[b][h][w][18] fp32 (pixel-major, (dy,dx) pairs per tap).
// Block: 16 cols x 8 rows; wave = 2 rows x 32 oc-slots (18 used).
// grid (12, 24, 4).
// -------------------------------------------------------------------------
__global__ __launch_bounds__(256) void k_conv_off_mfma(
    const ushort* __restrict__ xtb, const ushort* __restrict__ wOf,
    const float* __restrict__ b_off, float* __restrict__ offp) {
  const int w0 = blockIdx.x * 16;
  const int b = blockIdx.z;
  const int tid = threadIdx.x;
  const int wave = tid >> 6, lane = tid & 63;
  const int col = lane & 15, quad = lane >> 4;
  const int h0 = blockIdx.y * 8 + wave * 2;

  float4v acc[2][2];
#pragma unroll
  for (int mt = 0; mt < 2; ++mt)
#pragma unroll
    for (int nt = 0; nt < 2; ++nt) acc[mt][nt] = (float4v){0.f, 0.f, 0.f, 0.f};

#pragma unroll 1
  for (int kk = 0; kk < 9; ++kk) {
    const int ky = kk / 3, kx = kk % 3;
    const int ww = w0 + col + kx - 1;
    const bool wok = (unsigned)ww < (unsigned)W;
    const int wwc = min(max(ww, 0), W - 1);

    short8 bfr[2][2];
#pragma unroll
    for (int ks = 0; ks < 2; ++ks)
#pragma unroll
      for (int nt = 0; nt < 2; ++nt)
        bfr[ks][nt] = *(const short8*)&wOf[((((size_t)kk * 2 + ks) * 2 + nt) * 64 + lane) * 8];

    short8 afr[2][2];
#pragma unroll
    for (int mt = 0; mt < 2; ++mt) {
      const int hh = h0 + mt + ky - 1;
      const bool ok = wok && ((unsigned)hh < (unsigned)H);
      const int hhc = min(max(hh, 0), H - 1);
      const ushort* pa = xtb + (((size_t)b * H + hhc) * W + wwc) * C + quad * 8;
#pragma unroll
      for (int ks = 0; ks < 2; ++ks) {
        short8 v = (short8)0;
        if (ok) v = *(const short8*)(pa + ks * 32);
        afr[mt][ks] = v;
      }
    }
#pragma unroll
    for (int ks = 0; ks < 2; ++ks)
#pragma unroll
      for (int mt = 0; mt < 2; ++mt)
#pragma unroll
        for (int nt = 0; nt < 2; ++nt)
          acc[mt][nt] = __builtin_amdgcn_mfma_f32_16x16x32_bf16(afr[mt][ks], bfr[ks][nt],
                                                                acc[mt][nt], 0, 0, 0);
  }

#pragma unroll
  for (int mt = 0; mt < 2; ++mt) {
    const int h = h0 + mt;
#pragma unroll
    for (int nt = 0; nt < 2; ++nt) {
      const int o = nt * 16 + col;
      if (o < OOFF) {
        const float bias = b_off[o];
#pragma unroll
        for (int r = 0; r < 4; ++r) {
          const int w = w0 + quad * 4 + r;
          offp[(((size_t)b * H + h) * W + w) * OOFF + o] = acc[mt][nt][r] + bias;
        }
      }
    }
  }
}

// -------------------------------------------------------------------------
// Kernel 3: deformable conv, bf16 MFMA, software-pipelined gather.
// Tile 8x8 px (M=64), 256 threads = 4 waves; thread = (pixel, 16-ch quarter).
// Per kk: issue kk+1's 8 bf16 uint4 gather loads BEFORE blending kk;
// double-buffered LDS A-fragments, ONE barrier per kk. Offsets for all 9
// taps prefetched from pixel-major offp. Epilogue: bf16 channels-last yt.
// grid: 2304 blocks with XCD swizzle.
// -------------------------------------------------------------------------
__global__ __launch_bounds__(256, 3) void k_deform_mfma(
    const ushort* __restrict__ xtb, const float* __restrict__ offp,
    const ushort* __restrict__ wBf, const float* __restrict__ b_conv,
    ushort* __restrict__ yt) {
  __shared__ ushort sA[2][2][4][64][8]; // [buf][ks][mt][lane][j] = 16 KB

  const int bid = blockIdx.x;
  const int xcd = bid & 7;
  const int s = bid >> 3; // 0..287
  const int b = xcd >> 1;
  const int half = xcd & 1;
  const int th = half * 12 + s / 24; // 0..23
  const int tw = s % 24;             // 0..23
  const int h0 = th * 8, w0 = tw * 8;

  const int tid = threadIdx.x;
  const int wave = tid >> 6, lane = tid & 63;
  const int p = tid >> 2, qtr = tid & 3;
  const int prow = p >> 3, pcol = p & 7;
  const int h = h0 + prow, w = w0 + pcol;
  const int ks_w = qtr >> 1;    // LDS ks plane for this thread's writes
  const int q2 = (qtr & 1) * 2; // first quad row

  // prefetch all 9 offset pairs (contiguous 72 B per pixel)
  const float* po = offp + ((size_t)(b * H + h) * W + w) * OOFF;
  float2 offv[9];
#pragma unroll
  for (int kk = 0; kk < 9; ++kk) offv[kk] = *(const float2*)(po + 2 * kk);

  const ushort* xb = xtb + (size_t)b * H * W * C + qtr * 16;

  uint4 G[2][8]; // double-buffered gather registers (4 corners x 2 uint4)
  float4 aw[2];  // bilinear weights per buffer

  auto issue = [&](int kk, int buf) {
    const float dy = offv[kk].x, dx = offv[kk].y;
    const int ky = kk / 3, kx = kk % 3;
    const float pyf = dy + (float)(ky + h - 1);
    const float pxf = dx + (float)(kx + w - 1);
    const float fy0 = floorf(pyf), fx0 = floorf(pxf);
    const float wy = pyf - fy0, wx = pxf - fx0;
    const int iy0 = (int)fy0, ix0 = (int)fx0;
    const int iy1 = iy0 + 1, ix1 = ix0 + 1;
    const bool vy0 = (unsigned)iy0 < (unsigned)H;
    const bool vy1 = (unsigned)iy1 < (unsigned)H;
    const bool vx0 = (unsigned)ix0 < (unsigned)W;
    const bool vx1 = (unsigned)ix1 < (unsigned)W;
    aw[buf].x = (vy0 && vx0) ? (1.f - wy) * (1.f - wx) : 0.f;
    aw[buf].y = (vy0 && vx1) ? (1.f - wy) * wx : 0.f;
    aw[buf].z = (vy1 && vx0) ? wy * (1.f - wx) : 0.f;
    aw[buf].w = (vy1 && vx1) ? wy * wx : 0.f;
    const int cy0 = min(max(iy0, 0), H - 1), cy1 = min(max(iy1, 0), H - 1);
    const int cx0 = min(max(ix0, 0), W - 1), cx1 = min(max(ix1, 0), W - 1);
    const uint4* p00 = (const uint4*)(xb + ((size_t)cy0 * W + cx0) * C);
    const uint4* p01 = (const uint4*)(xb + ((size_t)cy0 * W + cx1) * C);
    const uint4* p10 = (const uint4*)(xb + ((size_t)cy1 * W + cx0) * C);
    const uint4* p11 = (const uint4*)(xb + ((size_t)cy1 * W + cx1) * C);
    G[buf][0] = p00[0]; G[buf][1] = p00[1];
    G[buf][2] = p01[0]; G[buf][3] = p01[1];
    G[buf][4] = p10[0]; G[buf][5] = p10[1];
    G[buf][6] = p11[0]; G[buf][7] = p11[1];
  };

  float4v acc[4];
#pragma unroll
  for (int nt = 0; nt < 4; ++nt) acc[nt] = (float4v){0.f, 0.f, 0.f, 0.f};

  issue(0, 0);
#pragma unroll
  for (int kk = 0; kk < 9; ++kk) {
    const int buf = kk & 1;
    if (kk < 8) issue(kk + 1, buf ^ 1); // next gather in flight during blend+MFMA

    const float a00 = aw[buf].x, a01 = aw[buf].y;
    const float a10 = aw[buf].z, a11 = aw[buf].w;
    uint pk[8];
#pragma unroll
    for (int i = 0; i < 8; ++i) {
      const uint u00 = ((const uint*)&G[buf][0])[i];
      const uint u01 = ((const uint*)&G[buf][2])[i];
      const uint u10 = ((const uint*)&G[buf][4])[i];
      const uint u11 = ((const uint*)&G[buf][6])[i];
      const float lo = __uint_as_float(u00 << 16) * a00 + __uint_as_float(u01 << 16) * a01 +
                       __uint_as_float(u10 << 16) * a10 + __uint_as_float(u11 << 16) * a11;
      const float hi = __uint_as_float(u00 & 0xffff0000u) * a00 +
                       __uint_as_float(u01 & 0xffff0000u) * a01 +
                       __uint_as_float(u10 & 0xffff0000u) * a10 +
                       __uint_as_float(u11 & 0xffff0000u) * a11;
      pk[i] = (uint)f2bf(lo) | ((uint)f2bf(hi) << 16);
    }
    *(uint4*)&sA[buf][ks_w][p >> 4][(p & 15) | (q2 << 4)][0] = *(const uint4*)&pk[0];
    *(uint4*)&sA[buf][ks_w][p >> 4][(p & 15) | ((q2 + 1) << 4)][0] = *(const uint4*)&pk[4];
    __syncthreads(); // single barrier: write(buf) -> read(buf); parity keeps reuse safe

#pragma unroll
    for (int ks = 0; ks < 2; ++ks) {
      const short8 a = *(const short8*)&sA[buf][ks][wave][lane][0];
#pragma unroll
      for (int nt = 0; nt < 4; ++nt) {
        const short8 bb = *(const short8*)&wBf[((((size_t)kk * 2 + ks) * 4 + nt) * 64 + lane) * 8];
        acc[nt] = __builtin_amdgcn_mfma_f32_16x16x32_bf16(a, bb, acc[nt], 0, 0, 0);
      }
    }
  }

  // epilogue: yt[b][h][w][c] bf16, oc = nt + 4*(lane&15) (permuted)
  const int quad = lane >> 4, c16 = lane & 15;
  float bias[4];
#pragma unroll
  for (int nt = 0; nt < 4; ++nt) bias[nt] = b_conv[4 * c16 + nt];
#pragma unroll
  for (int r = 0; r < 4; ++r) {
    const int pp = wave * 16 + quad * 4 + r; // pixel index in 8x8 tile
    const int hrow = h0 + (pp >> 3), wcol = w0 + (pp & 7);
    uint2 u;
    u.x = (uint)f2bf(acc[0][r] + bias[0]) | ((uint)f2bf(acc[1][r] + bias[1]) << 16);
    u.y = (uint)f2bf(acc[2][r] + bias[2]) | ((uint)f2bf(acc[3][r] + bias[3]) << 16);
    *(uint2*)&yt[((size_t)(b * H + hrow) * W + wcol) * C + 4 * c16] = u;
  }
}

// -------------------------------------------------------------------------
// Kernel 4: main 3x3 conv via bf16 MFMA, LDS-free. Wave = 2 rows x 64 oc;
// block = 8 rows; grid (12, 24, 4) = 1152 blocks.
// -------------------------------------------------------------------------
__global__ __launch_bounds__(256) void k_conv_main_mfma(
    const ushort* __restrict__ yt, const ushort* __restrict__ wBf,
    const float* __restrict__ b_conv, float* __restrict__ out) {
  const int w0 = blockIdx.x * 16;
  const int b = blockIdx.z;
  const int tid = threadIdx.x;
  const int wave = tid >> 6, lane = tid & 63;
  const int col = lane & 15, quad = lane >> 4;
  const int h0 = blockIdx.y * 8 + wave * 2;

  float4v acc[2][4];
#pragma unroll
  for (int mt = 0; mt < 2; ++mt)
#pragma unroll
    for (int nt = 0; nt < 4; ++nt) acc[mt][nt] = (float4v){0.f, 0.f, 0.f, 0.f};

#pragma unroll 1
  for (int kk = 0; kk < 9; ++kk) {
    const int ky = kk / 3, kx = kk % 3;
    const int ww = w0 + col + kx - 1;
    const bool wok = (unsigned)ww < (unsigned)W;
    const int wwc = min(max(ww, 0), W - 1);

    short8 bfr[2][4];
#pragma unroll
    for (int ks = 0; ks < 2; ++ks)
#pragma unroll
      for (int nt = 0; nt < 4; ++nt)
        bfr[ks][nt] = *(const short8*)&wBf[((((size_t)kk * 2 + ks) * 4 + nt) * 64 + lane) * 8];

    short8 afr[2][2];
#pragma unroll
    for (int mt = 0; mt < 2; ++mt) {
      const int hh = h0 + mt + ky - 1;
      const bool ok = wok && ((unsigned)hh < (unsigned)H);
      const int hhc = min(max(hh, 0), H - 1);
      const ushort* pa = yt + (((size_t)b * H + hhc) * W + wwc) * C + quad * 8;
#pragma unroll
      for (int ks = 0; ks < 2; ++ks) {
        short8 v = (short8)0;
        if (ok) v = *(const short8*)(pa + ks * 32);
        afr[mt][ks] = v;
      }
    }
#pragma unroll
    for (int ks = 0; ks < 2; ++ks)
#pragma unroll
      for (int mt = 0; mt < 2; ++mt)
#pragma unroll
        for (int nt = 0; nt < 4; ++nt)
          acc[mt][nt] = __builtin_amdgcn_mfma_f32_16x16x32_bf16(afr[mt][ks], bfr[ks][nt],
                                                                acc[mt][nt], 0, 0, 0);
  }

  float bias[4];
#pragma unroll
  for (int nt = 0; nt < 4; ++nt) bias[nt] = b_conv[4 * col + nt];
#pragma unroll
  for (int mt = 0; mt < 2; ++mt) {
    const int h = h0 + mt;
#pragma unroll
    for (int nt = 0; nt < 4; ++nt) {
      const int oc = 4 * col + nt; // permuted C/D col -> oc
      float4 v;
      v.x = acc[mt][nt][0] + bias[nt];
      v.y = acc[mt][nt][1] + bias[nt];
      v.z = acc[mt][nt][2] + bias[nt];
      v.w = acc[mt][nt][3] + bias[nt];
      *(float4*)&out[(((size_t)b * O + oc) * H + h) * W + w0 + quad * 4] = v;
    }
  }
}

// -------------------------------------------------------------------------
extern "C" void kernel_launch(void* const* d_in, const int* in_sizes, int n_in,
                              void* d_out, int out_size, void* d_ws, size_t ws_size,
                              hipStream_t stream) {
  const float* x = (const float*)d_in[0];
  const float* w_off = (const float*)d_in[1];
  const float* b_off = (const float*)d_in[2];
  const float* w_conv = (const float*)d_in[3];
  const float* b_conv = (const float*)d_in[4];
  float* out = (float*)d_out;

  float* offp = (float*)d_ws;                           // B*H*W*18 f32 (10.6 MB)
  ushort* xtb = (ushort*)(offp + (size_t)B * H * W * OOFF); // B*H*W*C bf16 (18.9 MB)
  ushort* yt = xtb + (size_t)B * H * W * C;                 // B*H*W*C bf16 (18.9 MB)
  ushort* wBf = yt + (size_t)B * H * W * C;                 // 36864 bf16
  ushort* wOf = wBf + 36864;                                // 18432 bf16

  const dim3 blk(256);
  k_prep_wB<<<dim3(144), blk, 0, stream>>>(w_conv, wBf);
  k_prep_wOff<<<dim3(72), blk, 0, stream>>>(w_off, wOf);
  k_transpose_bf<<<dim3(W / 16, H, B), blk, 0, stream>>>(x, xtb);
  k_conv_off_mfma<<<dim3(W / 16, H / 8, B), blk, 0, stream>>>(xtb, wOf, b_off, offp);
  k_deform_mfma<<<dim3(2304), blk, 0, stream>>>(xtb, offp, wBf, b_conv, yt);
  k_conv_main_mfma<<<dim3(W / 16, H / 8, B), blk, 0, stream>>>(yt, wBf, b_conv, out);
}

// Round 5
// 209.829 us; speedup vs baseline: 3.8654x; 1.0676x over previous
//
#include <hip/hip_runtime.h>

// Problem constants (fixed by setup_inputs)
constexpr int B = 4;
constexpr int C = 64;    // input channels
constexpr int O = 64;    // output channels (main conv)
constexpr int OOFF = 18; // offset channels = 2*3*3
constexpr int H = 192;
constexpr int W = 192;

typedef __attribute__((ext_vector_type(8))) short short8;   // 8 bf16 = 4 VGPR
typedef __attribute__((ext_vector_type(4))) float float4v;  // MFMA acc
typedef __attribute__((ext_vector_type(2))) float f32x2;    // v_pk_fma_f32 pair
typedef __attribute__((ext_vector_type(2))) uint u32x2;
typedef __attribute__((ext_vector_type(2))) __bf16 bf16x2;

__device__ inline ushort f2bf(float f) { // RNE via HW __bf16 convert
  return __builtin_bit_cast(ushort, (__bf16)f);
}
__device__ inline uint pk2bf(float lo, float hi) { // pack 2 bf16 (RNE)
  bf16x2 v;
  v.x = (__bf16)lo;
  v.y = (__bf16)hi;
  return __builtin_bit_cast(uint, v);
}
__device__ inline f32x2 upk(uint u) { // unpack 2 bf16 -> 2 f32
  u32x2 t;
  t.x = u << 16;
  t.y = u & 0xffff0000u;
  return __builtin_bit_cast(f32x2, t);
}

// -------------------------------------------------------------------------
// Kernel PRE (fused): blocks [0,9216): transpose x fp32 NCHW -> xtb bf16
// channels-last. Blocks [9216,9360): w_conv -> wBf B-fragments (PERMUTED
// n-map oc = nt + 4*col). Blocks [9360,9432): w_off -> wOf (plain n-map,
// N padded 18->32).
// -------------------------------------------------------------------------
__global__ __launch_bounds__(256) void k_pre(const float* __restrict__ x,
                                             ushort* __restrict__ xtb,
                                             const float* __restrict__ w_conv,
                                             ushort* __restrict__ wBf,
                                             const float* __restrict__ w_off,
                                             ushort* __restrict__ wOf) {
  __shared__ float tile[64][17];
  const int bid = blockIdx.x;
  const int tid = threadIdx.x;
  if (bid < 9216) { // transpose
    const int w0 = (bid % 12) * 16;
    const int h = (bid / 12) % 192;
    const int b = bid / 2304;
    const int wl = tid & 15;
    const int c0 = tid >> 4;
#pragma unroll
    for (int r = 0; r < 4; ++r) {
      const int c = c0 + r * 16;
      tile[c][wl] = x[(((size_t)b * C + c) * H + h) * W + w0 + wl];
    }
    __syncthreads();
    const int c = tid & 63;
    const int qq = tid >> 6;
#pragma unroll
    for (int r = 0; r < 4; ++r) {
      const int wq = qq + r * 4;
      xtb[(((size_t)b * H + h) * W + w0 + wq) * C + c] = f2bf(tile[c][wq]);
    }
  } else if (bid < 9360) { // wBf: 36864 entries
    const int i = (bid - 9216) * 256 + tid;
    const int j = i & 7;
    const int lane = (i >> 3) & 63;
    const int nt = (i >> 9) & 3;
    const int kstep = (i >> 11) & 1;
    const int kk = i >> 12;
    const int n = nt + 4 * (lane & 15); // permuted
    const int c = kstep * 32 + ((lane >> 4) & 3) * 8 + j;
    wBf[i] = f2bf(w_conv[((size_t)n * C + c) * 9 + kk]);
  } else { // wOf: 18432 entries
    const int i = (bid - 9360) * 256 + tid;
    const int j = i & 7;
    const int lane = (i >> 3) & 63;
    const int nt = (i >> 9) & 1;
    const int ks = (i >> 10) & 1;
    const int kk = i >> 11;
    const int n = nt * 16 + (lane & 15);
    const int c = ks * 32 + ((lane >> 4) & 3) * 8 + j;
    wOf[i] = (n < OOFF) ? f2bf(w_off[((size_t)n * C + c) * 9 + kk]) : (ushort)0;
  }
}

// -------------------------------------------------------------------------
// Kernel 2: offset conv via bf16 MFMA, LDS-free, 1-stage pipelined frags.
// Output offp[b][h][w][18] fp32 (pixel-major). Wave = 2 rows x 32 oc-slots.
// grid (12, 24, 4).
// -------------------------------------------------------------------------
__global__ __launch_bounds__(256) void k_conv_off_mfma(
    const ushort* __restrict__ xtb, const ushort* __restrict__ wOf,
    const float* __restrict__ b_off, float* __restrict__ offp) {
  const int w0 = blockIdx.x * 16;
  const int b = blockIdx.z;
  const int tid = threadIdx.x;
  const int wave = tid >> 6, lane = tid & 63;
  const int col = lane & 15, quad = lane >> 4;
  const int h0 = blockIdx.y * 8 + wave * 2;

  float4v acc[2][2];
#pragma unroll
  for (int mt = 0; mt < 2; ++mt)
#pragma unroll
    for (int nt = 0; nt < 2; ++nt) acc[mt][nt] = (float4v){0.f, 0.f, 0.f, 0.f};

  short8 bfr[2][2][2]; // [pb][ks][nt]
  short8 afr[2][2][2]; // [pb][mt][ks]

  auto load = [&](int kk, int pb) {
    const int ky = kk / 3, kx = kk % 3;
    const int ww = w0 + col + kx - 1;
    const bool wok = (unsigned)ww < (unsigned)W;
    const int wwc = min(max(ww, 0), W - 1);
#pragma unroll
    for (int ks = 0; ks < 2; ++ks)
#pragma unroll
      for (int nt = 0; nt < 2; ++nt)
        bfr[pb][ks][nt] = *(const short8*)&wOf[((((size_t)kk * 2 + ks) * 2 + nt) * 64 + lane) * 8];
#pragma unroll
    for (int mt = 0; mt < 2; ++mt) {
      const int hh = h0 + mt + ky - 1;
      const bool ok = wok && ((unsigned)hh < (unsigned)H);
      const int hhc = min(max(hh, 0), H - 1);
      const ushort* pa = xtb + (((size_t)b * H + hhc) * W + wwc) * C + quad * 8;
#pragma unroll
      for (int ks = 0; ks < 2; ++ks) {
        short8 v = (short8)0;
        if (ok) v = *(const short8*)(pa + ks * 32);
        afr[pb][mt][ks] = v;
      }
    }
  };

  load(0, 0);
#pragma unroll
  for (int kk = 0; kk < 9; ++kk) {
    const int pb = kk & 1;
    if (kk < 8) load(kk + 1, pb ^ 1);
#pragma unroll
    for (int ks = 0; ks < 2; ++ks)
#pragma unroll
      for (int mt = 0; mt < 2; ++mt)
#pragma unroll
        for (int nt = 0; nt < 2; ++nt)
          acc[mt][nt] = __builtin_amdgcn_mfma_f32_16x16x32_bf16(afr[pb][mt][ks], bfr[pb][ks][nt],
                                                                acc[mt][nt], 0, 0, 0);
  }

#pragma unroll
  for (int mt = 0; mt < 2; ++mt) {
    const int h = h0 + mt;
#pragma unroll
    for (int nt = 0; nt < 2; ++nt) {
      const int o = nt * 16 + col;
      if (o < OOFF) {
        const float bias = b_off[o];
#pragma unroll
        for (int r = 0; r < 4; ++r) {
          const int w = w0 + quad * 4 + r;
          offp[(((size_t)b * H + h) * W + w) * OOFF + o] = acc[mt][nt][r] + bias;
        }
      }
    }
  }
}

// -------------------------------------------------------------------------
// Kernel 3: deformable conv, bf16 MFMA, pipelined gather + PACKED blend.
// Tile 8x8 px (M=64), 256 threads = 4 waves; thread = (pixel, 16-ch quarter).
// Blend uses f32x2 (v_pk_fma_f32) + bf16x2 pack (v_cvt_pk_bf16_f32).
// grid: 2304 blocks with XCD swizzle.
// -------------------------------------------------------------------------
__global__ __launch_bounds__(256, 3) void k_deform_mfma(
    const ushort* __restrict__ xtb, const float* __restrict__ offp,
    const ushort* __restrict__ wBf, const float* __restrict__ b_conv,
    ushort* __restrict__ yt) {
  __shared__ ushort sA[2][2][4][64][8]; // [buf][ks][mt][lane][j] = 16 KB

  const int bid = blockIdx.x;
  const int xcd = bid & 7;
  const int s = bid >> 3; // 0..287
  const int b = xcd >> 1;
  const int half = xcd & 1;
  const int th = half * 12 + s / 24; // 0..23
  const int tw = s % 24;             // 0..23
  const int h0 = th * 8, w0 = tw * 8;

  const int tid = threadIdx.x;
  const int wave = tid >> 6, lane = tid & 63;
  const int p = tid >> 2, qtr = tid & 3;
  const int prow = p >> 3, pcol = p & 7;
  const int h = h0 + prow, w = w0 + pcol;
  const int ks_w = qtr >> 1;    // LDS ks plane for this thread's writes
  const int q2 = (qtr & 1) * 2; // first quad row

  // prefetch all 9 offset pairs (contiguous 72 B per pixel)
  const float* po = offp + ((size_t)(b * H + h) * W + w) * OOFF;
  float2 offv[9];
#pragma unroll
  for (int kk = 0; kk < 9; ++kk) offv[kk] = *(const float2*)(po + 2 * kk);

  const ushort* xb = xtb + (size_t)b * H * W * C + qtr * 16;

  uint4 G[2][8]; // double-buffered gather registers (4 corners x 2 uint4)
  float4 aw[2];  // bilinear weights per buffer

  auto issue = [&](int kk, int buf) {
    const float dy = offv[kk].x, dx = offv[kk].y;
    const int ky = kk / 3, kx = kk % 3;
    const float pyf = dy + (float)(ky + h - 1);
    const float pxf = dx + (float)(kx + w - 1);
    const float fy0 = floorf(pyf), fx0 = floorf(pxf);
    const float wy = pyf - fy0, wx = pxf - fx0;
    const int iy0 = (int)fy0, ix0 = (int)fx0;
    const int iy1 = iy0 + 1, ix1 = ix0 + 1;
    const bool vy0 = (unsigned)iy0 < (unsigned)H;
    const bool vy1 = (unsigned)iy1 < (unsigned)H;
    const bool vx0 = (unsigned)ix0 < (unsigned)W;
    const bool vx1 = (unsigned)ix1 < (unsigned)W;
    aw[buf].x = (vy0 && vx0) ? (1.f - wy) * (1.f - wx) : 0.f;
    aw[buf].y = (vy0 && vx1) ? (1.f - wy) * wx : 0.f;
    aw[buf].z = (vy1 && vx0) ? wy * (1.f - wx) : 0.f;
    aw[buf].w = (vy1 && vx1) ? wy * wx : 0.f;
    const int cy0 = min(max(iy0, 0), H - 1), cy1 = min(max(iy1, 0), H - 1);
    const int cx0 = min(max(ix0, 0), W - 1), cx1 = min(max(ix1, 0), W - 1);
    const uint4* p00 = (const uint4*)(xb + ((size_t)cy0 * W + cx0) * C);
    const uint4* p01 = (const uint4*)(xb + ((size_t)cy0 * W + cx1) * C);
    const uint4* p10 = (const uint4*)(xb + ((size_t)cy1 * W + cx0) * C);
    const uint4* p11 = (const uint4*)(xb + ((size_t)cy1 * W + cx1) * C);
    G[buf][0] = p00[0]; G[buf][1] = p00[1];
    G[buf][2] = p01[0]; G[buf][3] = p01[1];
    G[buf][4] = p10[0]; G[buf][5] = p10[1];
    G[buf][6] = p11[0]; G[buf][7] = p11[1];
  };

  float4v acc[4];
#pragma unroll
  for (int nt = 0; nt < 4; ++nt) acc[nt] = (float4v){0.f, 0.f, 0.f, 0.f};

  issue(0, 0);
#pragma unroll
  for (int kk = 0; kk < 9; ++kk) {
    const int buf = kk & 1;
    if (kk < 8) issue(kk + 1, buf ^ 1); // next gather in flight during blend+MFMA

    const f32x2 a00 = {aw[buf].x, aw[buf].x};
    const f32x2 a01 = {aw[buf].y, aw[buf].y};
    const f32x2 a10 = {aw[buf].z, aw[buf].z};
    const f32x2 a11 = {aw[buf].w, aw[buf].w};
    uint pk[8];
#pragma unroll
    for (int i = 0; i < 8; ++i) {
      const uint u00 = ((const uint*)&G[buf][0])[i];
      const uint u01 = ((const uint*)&G[buf][2])[i];
      const uint u10 = ((const uint*)&G[buf][4])[i];
      const uint u11 = ((const uint*)&G[buf][6])[i];
      f32x2 sv = upk(u00) * a00 + upk(u01) * a01 + upk(u10) * a10 + upk(u11) * a11;
      pk[i] = pk2bf(sv.x, sv.y);
    }
    *(uint4*)&sA[buf][ks_w][p >> 4][(p & 15) | (q2 << 4)][0] = *(const uint4*)&pk[0];
    *(uint4*)&sA[buf][ks_w][p >> 4][(p & 15) | ((q2 + 1) << 4)][0] = *(const uint4*)&pk[4];
    __syncthreads(); // single barrier: write(buf) -> read(buf); parity keeps reuse safe

#pragma unroll
    for (int ks = 0; ks < 2; ++ks) {
      const short8 a = *(const short8*)&sA[buf][ks][wave][lane][0];
#pragma unroll
      for (int nt = 0; nt < 4; ++nt) {
        const short8 bb = *(const short8*)&wBf[((((size_t)kk * 2 + ks) * 4 + nt) * 64 + lane) * 8];
        acc[nt] = __builtin_amdgcn_mfma_f32_16x16x32_bf16(a, bb, acc[nt], 0, 0, 0);
      }
    }
  }

  // epilogue: yt[b][h][w][c] bf16, oc = nt + 4*(lane&15) (permuted)
  const int quad = lane >> 4, c16 = lane & 15;
  float bias[4];
#pragma unroll
  for (int nt = 0; nt < 4; ++nt) bias[nt] = b_conv[4 * c16 + nt];
#pragma unroll
  for (int r = 0; r < 4; ++r) {
    const int pp = wave * 16 + quad * 4 + r; // pixel index in 8x8 tile
    const int hrow = h0 + (pp >> 3), wcol = w0 + (pp & 7);
    uint2 u;
    u.x = pk2bf(acc[0][r] + bias[0], acc[1][r] + bias[1]);
    u.y = pk2bf(acc[2][r] + bias[2], acc[3][r] + bias[3]);
    *(uint2*)&yt[((size_t)(b * H + hrow) * W + wcol) * C + 4 * c16] = u;
  }
}

// -------------------------------------------------------------------------
// Kernel 4: main 3x3 conv via bf16 MFMA, LDS-free, 1-stage pipelined frags.
// Wave = 2 rows x 64 oc; block = 8 rows; grid (12, 24, 4) = 1152 blocks.
// -------------------------------------------------------------------------
__global__ __launch_bounds__(256) void k_conv_main_mfma(
    const ushort* __restrict__ yt, const ushort* __restrict__ wBf,
    const float* __restrict__ b_conv, float* __restrict__ out) {
  const int w0 = blockIdx.x * 16;
  const int b = blockIdx.z;
  const int tid = threadIdx.x;
  const int wave = tid >> 6, lane = tid & 63;
  const int col = lane & 15, quad = lane >> 4;
  const int h0 = blockIdx.y * 8 + wave * 2;

  float4v acc[2][4];
#pragma unroll
  for (int mt = 0; mt < 2; ++mt)
#pragma unroll
    for (int nt = 0; nt < 4; ++nt) acc[mt][nt] = (float4v){0.f, 0.f, 0.f, 0.f};

  short8 bfr[2][2][4]; // [pb][ks][nt]
  short8 afr[2][2][2]; // [pb][mt][ks]

  auto load = [&](int kk, int pb) {
    const int ky = kk / 3, kx = kk % 3;
    const int ww = w0 + col + kx - 1;
    const bool wok = (unsigned)ww < (unsigned)W;
    const int wwc = min(max(ww, 0), W - 1);
#pragma unroll
    for (int ks = 0; ks < 2; ++ks)
#pragma unroll
      for (int nt = 0; nt < 4; ++nt)
        bfr[pb][ks][nt] = *(const short8*)&wBf[((((size_t)kk * 2 + ks) * 4 + nt) * 64 + lane) * 8];
#pragma unroll
    for (int mt = 0; mt < 2; ++mt) {
      const int hh = h0 + mt + ky - 1;
      const bool ok = wok && ((unsigned)hh < (unsigned)H);
      const int hhc = min(max(hh, 0), H - 1);
      const ushort* pa = yt + (((size_t)b * H + hhc) * W + wwc) * C + quad * 8;
#pragma unroll
      for (int ks = 0; ks < 2; ++ks) {
        short8 v = (short8)0;
        if (ok) v = *(const short8*)(pa + ks * 32);
        afr[pb][mt][ks] = v;
      }
    }
  };

  load(0, 0);
#pragma unroll
  for (int kk = 0; kk < 9; ++kk) {
    const int pb = kk & 1;
    if (kk < 8) load(kk + 1, pb ^ 1);
#pragma unroll
    for (int ks = 0; ks < 2; ++ks)
#pragma unroll
      for (int mt = 0; mt < 2; ++mt)
#pragma unroll
        for (int nt = 0; nt < 4; ++nt)
          acc[mt][nt] = __builtin_amdgcn_mfma_f32_16x16x32_bf16(afr[pb][mt][ks], bfr[pb][ks][nt],
                                                                acc[mt][nt], 0, 0, 0);
  }

  float bias[4];
#pragma unroll
  for (int nt = 0; nt < 4; ++nt) bias[nt] = b_conv[4 * col + nt];
#pragma unroll
  for (int mt = 0; mt < 2; ++mt) {
    const int h = h0 + mt;
#pragma unroll
    for (int nt = 0; nt < 4; ++nt) {
      const int oc = 4 * col + nt; // permuted C/D col -> oc
      float4 v;
      v.x = acc[mt][nt][0] + bias[nt];
      v.y = acc[mt][nt][1] + bias[nt];
      v.z = acc[mt][nt][2] + bias[nt];
      v.w = acc[mt][nt][3] + bias[nt];
      *(float4*)&out[(((size_t)b * O + oc) * H + h) * W + w0 + quad * 4] = v;
    }
  }
}

// -------------------------------------------------------------------------
extern "C" void kernel_launch(void* const* d_in, const int* in_sizes, int n_in,
                              void* d_out, int out_size, void* d_ws, size_t ws_size,
                              hipStream_t stream) {
  const float* x = (const float*)d_in[0];
  const float* w_off = (const float*)d_in[1];
  const float* b_off = (const float*)d_in[2];
  const float* w_conv = (const float*)d_in[3];
  const float* b_conv = (const float*)d_in[4];
  float* out = (float*)d_out;

  float* offp = (float*)d_ws;                               // B*H*W*18 f32
  ushort* xtb = (ushort*)(offp + (size_t)B * H * W * OOFF); // B*H*W*C bf16
  ushort* yt = xtb + (size_t)B * H * W * C;                 // B*H*W*C bf16
  ushort* wBf = yt + (size_t)B * H * W * C;                 // 36864 bf16
  ushort* wOf = wBf + 36864;                                // 18432 bf16

  const dim3 blk(256);
  k_pre<<<dim3(9432), blk, 0, stream>>>(x, xtb, w_conv, wBf, w_off, wOf);
  k_conv_off_mfma<<<dim3(W / 16, H / 8, B), blk, 0, stream>>>(xtb, wOf, b_off, offp);
  k_deform_mfma<<<dim3(2304), blk, 0, stream>>>(xtb, offp, wBf, b_conv, yt);
  k_conv_main_mfma<<<dim3(W / 16, H / 8, B), blk, 0, stream>>>(yt, wBf, b_conv, out);
}

// Round 6
// 197.646 us; speedup vs baseline: 4.1037x; 1.0616x over previous
//
#include <hip/hip_runtime.h>

// Problem constants (fixed by setup_inputs)
constexpr int B = 4;
constexpr int C = 64;    // input channels
constexpr int O = 64;    // output channels (main conv)
constexpr int OOFF = 18; // offset channels = 2*3*3
constexpr int H = 192;
constexpr int W = 192;

typedef __attribute__((ext_vector_type(8))) short short8;   // 8 bf16 = 4 VGPR
typedef __attribute__((ext_vector_type(4))) float float4v;  // MFMA acc
typedef __attribute__((ext_vector_type(2))) float f32x2;    // v_pk_fma_f32 pair
typedef __attribute__((ext_vector_type(2))) uint u32x2;
typedef __attribute__((ext_vector_type(2))) __bf16 bf16x2;

__device__ inline ushort f2bf(float f) { // RNE via HW __bf16 convert
  return __builtin_bit_cast(ushort, (__bf16)f);
}
__device__ inline uint pk2bf(float lo, float hi) { // pack 2 bf16 (RNE)
  bf16x2 v;
  v.x = (__bf16)lo;
  v.y = (__bf16)hi;
  return __builtin_bit_cast(uint, v);
}
__device__ inline f32x2 upk(uint u) { // unpack 2 bf16 -> 2 f32
  u32x2 t;
  t.x = u << 16;
  t.y = u & 0xffff0000u;
  return __builtin_bit_cast(f32x2, t);
}

// -------------------------------------------------------------------------
// Kernel PRE (fused): blocks [0,9216): transpose x fp32 NCHW -> xtb bf16
// channels-last. [9216,9360): w_conv -> wBf (PERMUTED n-map oc = nt+4*col).
// [9360,9432): w_off -> wOf (plain n-map, N padded 18->32).
// -------------------------------------------------------------------------
__global__ __launch_bounds__(256) void k_pre(const float* __restrict__ x,
                                             ushort* __restrict__ xtb,
                                             const float* __restrict__ w_conv,
                                             ushort* __restrict__ wBf,
                                             const float* __restrict__ w_off,
                                             ushort* __restrict__ wOf) {
  __shared__ float tile[64][17];
  const int bid = blockIdx.x;
  const int tid = threadIdx.x;
  if (bid < 9216) { // transpose
    const int w0 = (bid % 12) * 16;
    const int h = (bid / 12) % 192;
    const int b = bid / 2304;
    const int wl = tid & 15;
    const int c0 = tid >> 4;
#pragma unroll
    for (int r = 0; r < 4; ++r) {
      const int c = c0 + r * 16;
      tile[c][wl] = x[(((size_t)b * C + c) * H + h) * W + w0 + wl];
    }
    __syncthreads();
    const int c = tid & 63;
    const int qq = tid >> 6;
#pragma unroll
    for (int r = 0; r < 4; ++r) {
      const int wq = qq + r * 4;
      xtb[(((size_t)b * H + h) * W + w0 + wq) * C + c] = f2bf(tile[c][wq]);
    }
  } else if (bid < 9360) { // wBf: 36864 entries
    const int i = (bid - 9216) * 256 + tid;
    const int j = i & 7;
    const int lane = (i >> 3) & 63;
    const int nt = (i >> 9) & 3;
    const int kstep = (i >> 11) & 1;
    const int kk = i >> 12;
    const int n = nt + 4 * (lane & 15); // permuted
    const int c = kstep * 32 + ((lane >> 4) & 3) * 8 + j;
    wBf[i] = f2bf(w_conv[((size_t)n * C + c) * 9 + kk]);
  } else { // wOf: 18432 entries
    const int i = (bid - 9360) * 256 + tid;
    const int j = i & 7;
    const int lane = (i >> 3) & 63;
    const int nt = (i >> 9) & 1;
    const int ks = (i >> 10) & 1;
    const int kk = i >> 11;
    const int n = nt * 16 + (lane & 15);
    const int c = ks * 32 + ((lane >> 4) & 3) * 8 + j;
    wOf[i] = (n < OOFF) ? f2bf(w_off[((size_t)n * C + c) * 9 + kk]) : (ushort)0;
  }
}

// -------------------------------------------------------------------------
// Kernel FUSED: offset-conv + deformable conv, BARRIER-FREE.
// 8x8 px tile, 256 threads = 4 waves. All LDS exchange is intra-wave
// (gather thread (p,qtr) and MFMA lane for pixel p&15 share a wave), so no
// __syncthreads anywhere — waves run fully decoupled pipelines.
// Phase 1: per-wave 16px x 32oc(18) x K576 MFMA GEMM for offsets (LDS-free
//          A/B loads, conv_main pattern); offsets -> per-wave LDS slab.
// Phase 2: pipelined bilinear gather (packed blend) -> per-wave sA frag
//          slab -> 72 MFMA; epilogue -> bf16 channels-last yt.
// grid: 2304 blocks with XCD swizzle.
// -------------------------------------------------------------------------
__global__ __launch_bounds__(256) void k_fused(
    const ushort* __restrict__ xtb, const ushort* __restrict__ wOf,
    const float* __restrict__ b_off, const ushort* __restrict__ wBf,
    const float* __restrict__ b_conv, ushort* __restrict__ yt) {
  __shared__ ushort sA[4][2][64][8];              // [wave][ks][lane][j] = 8 KB
  __shared__ __align__(16) float offBuf[4][16][20]; // [wave][pl][oc(18,pad20)] = 5 KB

  const int bid = blockIdx.x;
  const int xcd = bid & 7;
  const int s = bid >> 3; // 0..287
  const int b = xcd >> 1;
  const int half = xcd & 1;
  const int th = half * 12 + s / 24; // 0..23
  const int tw = s % 24;             // 0..23
  const int h0 = th * 8, w0 = tw * 8;

  const int tid = threadIdx.x;
  const int wave = tid >> 6, lane = tid & 63;
  const int col = lane & 15, quad = lane >> 4;
  const int p = tid >> 2, qtr = tid & 3;
  const int pl = p & 15; // wave-local pixel
  const int prow = p >> 3, pcol = p & 7;
  const int h = h0 + prow, w = w0 + pcol;
  const int ks_w = qtr >> 1;    // LDS ks plane for gather writes
  const int q2 = (qtr & 1) * 2; // first quad row

  // ===================== Phase 1: offset conv (per wave) =====================
  {
    float4v oacc[2];
#pragma unroll
    for (int nt = 0; nt < 2; ++nt) oacc[nt] = (float4v){0.f, 0.f, 0.f, 0.f};

    short8 obfr[2][2][2]; // [pb][ks][nt]
    short8 oafr[2][2];    // [pb][ks]

    auto oload = [&](int kk, int pb) {
      const int ky = kk / 3, kx = kk % 3;
      const int hh = h0 + 2 * wave + (col >> 3) + ky - 1;
      const int ww = w0 + (col & 7) + kx - 1;
      const bool ok = ((unsigned)hh < (unsigned)H) && ((unsigned)ww < (unsigned)W);
      const int hhc = min(max(hh, 0), H - 1);
      const int wwc = min(max(ww, 0), W - 1);
      const ushort* pa = xtb + (((size_t)b * H + hhc) * W + wwc) * C + quad * 8;
#pragma unroll
      for (int ks = 0; ks < 2; ++ks) {
        short8 v = (short8)0;
        if (ok) v = *(const short8*)(pa + ks * 32);
        oafr[pb][ks] = v;
#pragma unroll
        for (int nt = 0; nt < 2; ++nt)
          obfr[pb][ks][nt] = *(const short8*)&wOf[((((size_t)kk * 2 + ks) * 2 + nt) * 64 + lane) * 8];
      }
    };

    oload(0, 0);
#pragma unroll
    for (int kk = 0; kk < 9; ++kk) {
      const int pb = kk & 1;
      if (kk < 8) oload(kk + 1, pb ^ 1);
#pragma unroll
      for (int ks = 0; ks < 2; ++ks)
#pragma unroll
        for (int nt = 0; nt < 2; ++nt)
          oacc[nt] = __builtin_amdgcn_mfma_f32_16x16x32_bf16(oafr[pb][ks], obfr[pb][ks][nt],
                                                             oacc[nt], 0, 0, 0);
    }

    // distribute offsets: D[m=quad*4+r][n=nt*16+col] -> offBuf[wave][m][oc]
#pragma unroll
    for (int nt = 0; nt < 2; ++nt) {
      const int oc = nt * 16 + col;
      if (oc < OOFF) {
        const float bias = b_off[oc];
#pragma unroll
        for (int r = 0; r < 4; ++r)
          offBuf[wave][quad * 4 + r][oc] = oacc[nt][r] + bias;
      }
    }
  } // intra-wave LDS exchange: no barrier needed (same-wave ds ordering)

  // ===================== Phase 2: deformable conv =====================
  const ushort* xb = xtb + (size_t)b * H * W * C + qtr * 16;

  uint4 G[2][8]; // double-buffered gather registers (4 corners x 2 uint4)
  float4 aw[2];  // bilinear weights per buffer

  auto issue = [&](int kk, int buf) {
    const float2 ov = *(const float2*)&offBuf[wave][pl][2 * kk];
    const float dy = ov.x, dx = ov.y;
    const int ky = kk / 3, kx = kk % 3;
    const float pyf = dy + (float)(ky + h - 1);
    const float pxf = dx + (float)(kx + w - 1);
    const float fy0 = floorf(pyf), fx0 = floorf(pxf);
    const float wy = pyf - fy0, wx = pxf - fx0;
    const int iy0 = (int)fy0, ix0 = (int)fx0;
    const int iy1 = iy0 + 1, ix1 = ix0 + 1;
    const bool vy0 = (unsigned)iy0 < (unsigned)H;
    const bool vy1 = (unsigned)iy1 < (unsigned)H;
    const bool vx0 = (unsigned)ix0 < (unsigned)W;
    const bool vx1 = (unsigned)ix1 < (unsigned)W;
    aw[buf].x = (vy0 && vx0) ? (1.f - wy) * (1.f - wx) : 0.f;
    aw[buf].y = (vy0 && vx1) ? (1.f - wy) * wx : 0.f;
    aw[buf].z = (vy1 && vx0) ? wy * (1.f - wx) : 0.f;
    aw[buf].w = (vy1 && vx1) ? wy * wx : 0.f;
    const int cy0 = min(max(iy0, 0), H - 1), cy1 = min(max(iy1, 0), H - 1);
    const int cx0 = min(max(ix0, 0), W - 1), cx1 = min(max(ix1, 0), W - 1);
    const uint4* p00 = (const uint4*)(xb + ((size_t)cy0 * W + cx0) * C);
    const uint4* p01 = (const uint4*)(xb + ((size_t)cy0 * W + cx1) * C);
    const uint4* p10 = (const uint4*)(xb + ((size_t)cy1 * W + cx0) * C);
    const uint4* p11 = (const uint4*)(xb + ((size_t)cy1 * W + cx1) * C);
    G[buf][0] = p00[0]; G[buf][1] = p00[1];
    G[buf][2] = p01[0]; G[buf][3] = p01[1];
    G[buf][4] = p10[0]; G[buf][5] = p10[1];
    G[buf][6] = p11[0]; G[buf][7] = p11[1];
  };

  float4v acc[4];
#pragma unroll
  for (int nt = 0; nt < 4; ++nt) acc[nt] = (float4v){0.f, 0.f, 0.f, 0.f};

  issue(0, 0);
#pragma unroll
  for (int kk = 0; kk < 9; ++kk) {
    const int buf = kk & 1;
    if (kk < 8) issue(kk + 1, buf ^ 1); // next gather in flight during blend+MFMA

    const f32x2 a00 = {aw[buf].x, aw[buf].x};
    const f32x2 a01 = {aw[buf].y, aw[buf].y};
    const f32x2 a10 = {aw[buf].z, aw[buf].z};
    const f32x2 a11 = {aw[buf].w, aw[buf].w};
    uint pk[8];
#pragma unroll
    for (int i = 0; i < 8; ++i) {
      const uint u00 = ((const uint*)&G[buf][0])[i];
      const uint u01 = ((const uint*)&G[buf][2])[i];
      const uint u10 = ((const uint*)&G[buf][4])[i];
      const uint u11 = ((const uint*)&G[buf][6])[i];
      f32x2 sv = upk(u00) * a00 + upk(u01) * a01 + upk(u10) * a10 + upk(u11) * a11;
      pk[i] = pk2bf(sv.x, sv.y);
    }
    // intra-wave exchange: write own wave's slab, read it back below; the
    // compiler's lgkmcnt insertion orders same-wave ds_write -> ds_read.
    *(uint4*)&sA[wave][ks_w][pl | (q2 << 4)][0] = *(const uint4*)&pk[0];
    *(uint4*)&sA[wave][ks_w][pl | ((q2 + 1) << 4)][0] = *(const uint4*)&pk[4];

#pragma unroll
    for (int ks = 0; ks < 2; ++ks) {
      const short8 a = *(const short8*)&sA[wave][ks][lane][0];
#pragma unroll
      for (int nt = 0; nt < 4; ++nt) {
        const short8 bb = *(const short8*)&wBf[((((size_t)kk * 2 + ks) * 4 + nt) * 64 + lane) * 8];
        acc[nt] = __builtin_amdgcn_mfma_f32_16x16x32_bf16(a, bb, acc[nt], 0, 0, 0);
      }
    }
  }

  // epilogue: yt[b][h][w][c] bf16, oc = nt + 4*(lane&15) (permuted)
  float bias[4];
#pragma unroll
  for (int nt = 0; nt < 4; ++nt) bias[nt] = b_conv[4 * col + nt];
#pragma unroll
  for (int r = 0; r < 4; ++r) {
    const int pp = wave * 16 + quad * 4 + r; // pixel index in 8x8 tile
    const int hrow = h0 + (pp >> 3), wcol = w0 + (pp & 7);
    uint2 u;
    u.x = pk2bf(acc[0][r] + bias[0], acc[1][r] + bias[1]);
    u.y = pk2bf(acc[2][r] + bias[2], acc[3][r] + bias[3]);
    *(uint2*)&yt[((size_t)(b * H + hrow) * W + wcol) * C + 4 * col] = u;
  }
}

// -------------------------------------------------------------------------
// Kernel 4: main 3x3 conv via bf16 MFMA, LDS-free, 1-stage pipelined frags.
// Wave = 2 rows x 64 oc; block = 8 rows; grid (12, 24, 4) = 1152 blocks.
// -------------------------------------------------------------------------
__global__ __launch_bounds__(256) void k_conv_main_mfma(
    const ushort* __restrict__ yt, const ushort* __restrict__ wBf,
    const float* __restrict__ b_conv, float* __restrict__ out) {
  const int w0 = blockIdx.x * 16;
  const int b = blockIdx.z;
  const int tid = threadIdx.x;
  const int wave = tid >> 6, lane = tid & 63;
  const int col = lane & 15, quad = lane >> 4;
  const int h0 = blockIdx.y * 8 + wave * 2;

  float4v acc[2][4];
#pragma unroll
  for (int mt = 0; mt < 2; ++mt)
#pragma unroll
    for (int nt = 0; nt < 4; ++nt) acc[mt][nt] = (float4v){0.f, 0.f, 0.f, 0.f};

  short8 bfr[2][2][4]; // [pb][ks][nt]
  short8 afr[2][2][2]; // [pb][mt][ks]

  auto load = [&](int kk, int pb) {
    const int ky = kk / 3, kx = kk % 3;
    const int ww = w0 + col + kx - 1;
    const bool wok = (unsigned)ww < (unsigned)W;
    const int wwc = min(max(ww, 0), W - 1);
#pragma unroll
    for (int ks = 0; ks < 2; ++ks)
#pragma unroll
      for (int nt = 0; nt < 4; ++nt)
        bfr[pb][ks][nt] = *(const short8*)&wBf[((((size_t)kk * 2 + ks) * 4 + nt) * 64 + lane) * 8];
#pragma unroll
    for (int mt = 0; mt < 2; ++mt) {
      const int hh = h0 + mt + ky - 1;
      const bool ok = wok && ((unsigned)hh < (unsigned)H);
      const int hhc = min(max(hh, 0), H - 1);
      const ushort* pa = yt + (((size_t)b * H + hhc) * W + wwc) * C + quad * 8;
#pragma unroll
      for (int ks = 0; ks < 2; ++ks) {
        short8 v = (short8)0;
        if (ok) v = *(const short8*)(pa + ks * 32);
        afr[pb][mt][ks] = v;
      }
    }
  };

  load(0, 0);
#pragma unroll
  for (int kk = 0; kk < 9; ++kk) {
    const int pb = kk & 1;
    if (kk < 8) load(kk + 1, pb ^ 1);
#pragma unroll
    for (int ks = 0; ks < 2; ++ks)
#pragma unroll
      for (int mt = 0; mt < 2; ++mt)
#pragma unroll
        for (int nt = 0; nt < 4; ++nt)
          acc[mt][nt] = __builtin_amdgcn_mfma_f32_16x16x32_bf16(afr[pb][mt][ks], bfr[pb][ks][nt],
                                                                acc[mt][nt], 0, 0, 0);
  }

  float bias[4];
#pragma unroll
  for (int nt = 0; nt < 4; ++nt) bias[nt] = b_conv[4 * col + nt];
#pragma unroll
  for (int mt = 0; mt < 2; ++mt) {
    const int h = h0 + mt;
#pragma unroll
    for (int nt = 0; nt < 4; ++nt) {
      const int oc = 4 * col + nt; // permuted C/D col -> oc
      float4 v;
      v.x = acc[mt][nt][0] + bias[nt];
      v.y = acc[mt][nt][1] + bias[nt];
      v.z = acc[mt][nt][2] + bias[nt];
      v.w = acc[mt][nt][3] + bias[nt];
      *(float4*)&out[(((size_t)b * O + oc) * H + h) * W + w0 + quad * 4] = v;
    }
  }
}

// -------------------------------------------------------------------------
extern "C" void kernel_launch(void* const* d_in, const int* in_sizes, int n_in,
                              void* d_out, int out_size, void* d_ws, size_t ws_size,
                              hipStream_t stream) {
  const float* x = (const float*)d_in[0];
  const float* w_off = (const float*)d_in[1];
  const float* b_off = (const float*)d_in[2];
  const float* w_conv = (const float*)d_in[3];
  const float* b_conv = (const float*)d_in[4];
  float* out = (float*)d_out;

  ushort* xtb = (ushort*)d_ws;              // B*H*W*C bf16
  ushort* yt = xtb + (size_t)B * H * W * C; // B*H*W*C bf16
  ushort* wBf = yt + (size_t)B * H * W * C; // 36864 bf16
  ushort* wOf = wBf + 36864;                // 18432 bf16

  const dim3 blk(256);
  k_pre<<<dim3(9432), blk, 0, stream>>>(x, xtb, w_conv, wBf, w_off, wOf);
  k_fused<<<dim3(2304), blk, 0, stream>>>(xtb, wOf, b_off, wBf, b_conv, yt);
  k_conv_main_mfma<<<dim3(W / 16, H / 8, B), blk, 0, stream>>>(yt, wBf, b_conv, out);
}